// Round 5
// baseline (17808.691 us; speedup 1.0000x reference)
//
#include <hip/hip_runtime.h>
#include <math.h>

// 512 rows of length 8192. Power iteration b <- normalize(b - T(x)C(c)b), 100x,
// then sigma = b.(b - TCb); out = mean(|sigma|).
//
// ROUND 15 KEY CHANGE: 2 rows per 1024-thread workgroup. Evidence trail:
//   - VALUBusy ~25%, Occupancy ~24% (= 8 waves/CU = 2 waves/SIMD) every round;
//     ~2 ms of VALU work stretched to 8 ms -> latency/barrier-bound with no TLP.
//   - Something (scratch? scheduler) refuses a 2nd resident 512-thread block at
//     ANY LDS size (70 KB rounds 0-1, 139 KB rounds 3-4: occupancy 24% always).
//   - Both VGPR-budget overrides (launch_bounds 2nd arg, amdgpu_waves_per_eu)
//     were ignored (VGPR_Count pinned at 128).
//   Fix: fuse 2 rows into one 1024-thread block -> 16 waves/CU inside ONE
//   block, sidestepping the 2nd-block residency limit entirely. Per-thread
//   code identical: t = tid&511, row = 2*bid + (tid>>9), per-half buf/red.
//   G spectrum back in global (round-0 junction loads, minimal liveness);
//   two 70 KB FFT buffers = 139,328 B LDS -> 1 block/CU, 4 waves/SIMD.
//
// LDS layout: classic FFT padding a(e) = e + (e>>4) (one float2 pad per 16).
// Every stage's accesses are base + affine-stride*k -> single address VGPR
// + ds imm offsets; conflict-free at b64 (each bank-pair hit exactly 4x/64).
//
// Padded bases (derived exactly, no runtime >>4 of sums):
//   S1:     a = t+(t>>4) + 544q, mirror +4352
//   stage2: a = (t>>8)*4352 + m+(m>>4) + 272k,  m = t&255
//   stage3: a = (t>>4)*272 + (t&15) + 17k
//   mid:    a = 17t + k

#define NN 8192
#define NT 512
#define ROWS 512
#define BUFSZ 8704   // 8192 + 512 pad (float2)

__device__ __forceinline__ float2 cadd(float2 a, float2 b){ return make_float2(a.x+b.x, a.y+b.y); }
__device__ __forceinline__ float2 csub(float2 a, float2 b){ return make_float2(a.x-b.x, a.y-b.y); }
__device__ __forceinline__ float2 cmul(float2 a, float2 b){
  return make_float2(fmaf(a.x, b.x, -(a.y*b.y)), fmaf(a.x, b.y, a.y*b.x));
}
__device__ __forceinline__ float2 cscale(float2 a, float s){ return make_float2(a.x*s, a.y*s); }
__device__ __forceinline__ float2 conjf2(float2 a){ return make_float2(a.x, -a.y); }

static constexpr int PM[16] = {0,4,8,12,1,5,9,13,2,6,10,14,3,7,11,15}; // involution

template<bool P> __device__ __forceinline__ constexpr int IX(int i){ return P ? PM[i] : i; }

template<int DIR> // DIR = -1 forward, +1 inverse
__device__ __forceinline__ void dft4(float2& a, float2& b, float2& c, float2& d){
  float2 t0=cadd(a,c), t1=csub(a,c), t2=cadd(b,d), t3=csub(b,d);
  float2 it3 = make_float2((float)(-DIR)*t3.y, (float)DIR*t3.x);
  a = cadd(t0,t2);
  c = csub(t0,t2);
  b = cadd(t1,it3);
  d = csub(t1,it3);
}

template<int DIR, bool P>
__device__ __forceinline__ void dft16i(float2 y[16]){
  dft4<DIR>(y[IX<P>(0)],y[IX<P>(4)],y[IX<P>(8)], y[IX<P>(12)]);
  dft4<DIR>(y[IX<P>(1)],y[IX<P>(5)],y[IX<P>(9)], y[IX<P>(13)]);
  dft4<DIR>(y[IX<P>(2)],y[IX<P>(6)],y[IX<P>(10)],y[IX<P>(14)]);
  dft4<DIR>(y[IX<P>(3)],y[IX<P>(7)],y[IX<P>(11)],y[IX<P>(15)]);
  const float C1=0.92387953251f, S1f=0.38268343236f, C2=0.70710678119f;
  const float D=(float)DIR;
  y[IX<P>(5)]  = cmul(y[IX<P>(5)],  make_float2(C1,  D*S1f));
  y[IX<P>(6)]  = cmul(y[IX<P>(6)],  make_float2(C2,  D*C2));
  y[IX<P>(7)]  = cmul(y[IX<P>(7)],  make_float2(S1f, D*C1));
  y[IX<P>(9)]  = cmul(y[IX<P>(9)],  make_float2(C2,  D*C2));
  y[IX<P>(10)] = cmul(y[IX<P>(10)], make_float2(0.f, D));
  y[IX<P>(11)] = cmul(y[IX<P>(11)], make_float2(-C2, D*C2));
  y[IX<P>(13)] = cmul(y[IX<P>(13)], make_float2(S1f, D*C1));
  y[IX<P>(14)] = cmul(y[IX<P>(14)], make_float2(-C2, D*C2));
  y[IX<P>(15)] = cmul(y[IX<P>(15)], make_float2(-C1, -D*S1f));
  dft4<DIR>(y[IX<P>(0)], y[IX<P>(1)], y[IX<P>(2)], y[IX<P>(3)]);
  dft4<DIR>(y[IX<P>(4)], y[IX<P>(5)], y[IX<P>(6)], y[IX<P>(7)]);
  dft4<DIR>(y[IX<P>(8)], y[IX<P>(9)], y[IX<P>(10)],y[IX<P>(11)]);
  dft4<DIR>(y[IX<P>(12)],y[IX<P>(13)],y[IX<P>(14)],y[IX<P>(15)]);
}

// Middle forward stage: buf[a0 + st*k], affine -> imm offsets.
__device__ __forceinline__ void fwd_stage16(float2* buf, int a0, int st, float2 w){
  float2 y[16];
  #pragma unroll
  for(int k=0;k<16;k++) y[k] = buf[a0 + st*k];
  dft16i<-1,false>(y);
  float2 tw = make_float2(1.f,0.f);
  #pragma unroll
  for(int j=0;j<16;j++){
    buf[a0 + st*j] = cmul(y[PM[j]], tw);
    tw = cmul(tw, w);
  }
}

// Middle inverse stage.
__device__ __forceinline__ void inv_stage16(float2* buf, int a0, int st, float2 w){
  float2 y[16];
  float2 tw = make_float2(1.f,0.f);
  #pragma unroll
  for(int j=0;j<16;j++){
    y[j] = cmul(buf[a0 + st*j], tw);
    tw = cmul(tw, w);
  }
  dft16i<1,false>(y);
  #pragma unroll
  for(int i=0;i<16;i++) buf[a0 + st*PM[i]] = y[i];
}

// Plain last forward stage (precompute only): stores slot aM+j = Spec[j].
__device__ __forceinline__ void fwd_stage_last(float2* buf, int aM){
  float2 y[16];
  #pragma unroll
  for(int k=0;k<16;k++) y[k] = buf[aM + k];
  dft16i<-1,false>(y);
  #pragma unroll
  for(int j=0;j<16;j++) buf[aM + j] = y[PM[j]];
}

// Fused: fwd-last-stage + spectrum multiply + inv-first-stage, in registers.
// MODE 1: p = 8 float4 = complex G[16t+0..15]. MODE 2: p = 4 float4 = real s[16].
// Loads happen AT the multiply (behind a fence) to minimize liveness.
template<int MODE>
__device__ __forceinline__ void mid_junction(float2* buf, int aM, const float4* p){
  float2 y[16];
  #pragma unroll
  for(int k=0;k<16;k++) y[k] = buf[aM + k];
  dft16i<-1,false>(y);
  asm volatile("" ::: "memory");
  if (MODE==1) {
    #pragma unroll
    for(int j4=0;j4<8;j4++){
      float4 a = p[j4];
      y[PM[2*j4]]   = cmul(y[PM[2*j4]],   make_float2(a.x, a.y));
      y[PM[2*j4+1]] = cmul(y[PM[2*j4+1]], make_float2(a.z, a.w));
    }
  } else {
    #pragma unroll
    for(int j4=0;j4<4;j4++){
      float4 a = p[j4];
      y[PM[4*j4]]   = cscale(y[PM[4*j4]],   a.x);
      y[PM[4*j4+1]] = cscale(y[PM[4*j4+1]], a.y);
      y[PM[4*j4+2]] = cscale(y[PM[4*j4+2]], a.z);
      y[PM[4*j4+3]] = cscale(y[PM[4*j4+3]], a.w);
    }
  }
  dft16i<1,true>(y);
  #pragma unroll
  for(int k=0;k<16;k++) buf[aM + k] = y[k];
}

// S1 (radix-2) from real regs b[j] = v[t+512j]. aS1 = t+(t>>4).
__device__ __forceinline__ void fwd_s1_real(float2* buf, int aS1, const float b[16], float2 w1){
  float2 tw = w1;
  const float2 step = make_float2(0.92387953251f, -0.38268343236f); // e^{-i pi/8}
  #pragma unroll
  for(int q=0;q<8;q++){
    int a = aS1 + 544*q;
    float d = b[q] - b[q+8];
    buf[a]        = make_float2(b[q] + b[q+8], 0.f);
    buf[a + 4352] = make_float2(d*tw.x, d*tw.y);
    tw = cmul(tw, step);
  }
}

// S1 (radix-2) from complex regs (precompute only).
__device__ __forceinline__ void fwd_s1_cplx(float2* buf, int aS1, const float2 in[16], float2 w1){
  float2 tw = w1;
  const float2 step = make_float2(0.92387953251f, -0.38268343236f);
  #pragma unroll
  for(int q=0;q<8;q++){
    int a = aS1 + 544*q;
    buf[a]        = cadd(in[q], in[q+8]);
    buf[a + 4352] = cmul(csub(in[q], in[q+8]), tw);
    tw = cmul(tw, step);
  }
}

// Fused: inv-S1 (end FFT1-IFFT) + epilogue1 + phi-modulate + fwd-S1 (FFT2).
template<bool SIGMA>
__device__ __forceinline__ void s1_junction(float2* buf, int aS1, float breg[16], float& loc,
                                            float2 w1, float pc, float ps, float sc1){
  float2 twi = conjf2(w1), twf = w1;
  const float2 stepi = make_float2(0.92387953251f,  0.38268343236f);
  const float2 stepf = make_float2(0.92387953251f, -0.38268343236f);
  float2 ph = make_float2(pc, ps);
  const float2 phstep = make_float2(0.98078528040f, -0.19509032202f); // e^{-i pi/16}
  #pragma unroll
  for(int q=0;q<8;q++){
    int a = aS1 + 544*q;
    float2 z0 = buf[a];
    float2 z1 = cmul(buf[a + 4352], twi);
    float2 zn = cscale(cadd(z0,z1), sc1);   // u_n + i*hx1_n
    float2 zm = cscale(csub(z0,z1), sc1);   // u_m + i*hx1_m
    if (SIGMA) {
      loc += breg[q]*(breg[q]-zn.y) + breg[q+8]*(breg[q+8]-zm.y);
    } else {
      breg[q]   -= zn.y;
      breg[q+8] -= zm.y;
    }
    float2 vn = make_float2(zn.x*ph.x,  zn.x*ph.y);
    float2 vm = make_float2(zm.x*ph.y, -zm.x*ph.x);
    buf[a]        = cadd(vn, vm);
    buf[a + 4352] = cmul(csub(vn, vm), twf);
    twi = cmul(twi, stepi); twf = cmul(twf, stepf); ph = cmul(ph, phstep);
  }
}

// Fused: inv-S1 (end FFT2-IFFT) + epilogue2.
template<bool SIGMA>
__device__ __forceinline__ void s1_final(float2* buf, int aS1, float breg[16], float& loc,
                                         float2 w1, float pc, float ps, float sc2){
  float2 twi = conjf2(w1);
  const float2 stepi = make_float2(0.92387953251f, 0.38268343236f);
  float2 ph = make_float2(pc, ps);
  const float2 phstep = make_float2(0.98078528040f, -0.19509032202f);
  #pragma unroll
  for(int q=0;q<8;q++){
    int a = aS1 + 544*q;
    float2 z0 = buf[a];
    float2 z1 = cmul(buf[a + 4352], twi);
    float2 yn = cscale(cadd(z0,z1), sc2);
    float2 ym = cscale(csub(z0,z1), sc2);
    float qn = fmaf(ph.x, yn.x,  ph.y*yn.y);     // Re(conj(ph)*yn)
    float qm = fmaf(ph.y, ym.x, -ph.x*ym.y);     // Re(i*conj(ph)*ym)
    if (SIGMA) {
      loc -= breg[q]*qn + breg[q+8]*qm;
    } else {
      float bn = breg[q]   - qn; breg[q]   = bn; loc = fmaf(bn,bn,loc);
      bn       = breg[q+8] - qm; breg[q+8] = bn; loc = fmaf(bn,bn,loc);
    }
    twi = cmul(twi, stepi); ph = cmul(ph, phstep);
  }
}

// One full iteration body (4 FFTs + epilogues + per-row reduction); returns tot.
// NOTE: __syncthreads() spans BOTH rows of the 1024-thread block; rows have
// identical work so lockstep coupling is negligible.
template<bool SIGMA>
__device__ __forceinline__ float iterate(float2* buf, float* red, int t, float breg[16],
                                         int aS1, int a2, int a3, int aM,
                                         float2 w1, float2 w2, float2 w3, float pc, float ps,
                                         const float4* gptr, const float4* sptr){
  const float sc1 = 1.f/8192.f, sc2 = 1.f/8192.f;
  float loc = 0.f;

  fwd_s1_real(buf, aS1, breg, w1);
  __syncthreads();
  fwd_stage16(buf, a2, 272, w2);
  __syncthreads();
  fwd_stage16(buf, a3, 17,  w3);
  __syncthreads();
  mid_junction<1>(buf, aM, gptr);                    // *G (loaded in-place)
  __syncthreads();
  inv_stage16(buf, a3, 17,  conjf2(w3));
  __syncthreads();
  inv_stage16(buf, a2, 272, conjf2(w2));
  __syncthreads();
  s1_junction<SIGMA>(buf, aS1, breg, loc, w1, pc, ps, sc1);
  __syncthreads();
  fwd_stage16(buf, a2, 272, w2);
  __syncthreads();
  fwd_stage16(buf, a3, 17,  w3);
  __syncthreads();
  mid_junction<2>(buf, aM, sptr);                    // *0.5*S2o (loaded in-place)
  __syncthreads();
  inv_stage16(buf, a3, 17,  conjf2(w3));
  __syncthreads();
  inv_stage16(buf, a2, 272, conjf2(w2));
  __syncthreads();
  s1_final<SIGMA>(buf, aS1, breg, loc, w1, pc, ps, sc2);

  __syncthreads();
  #pragma unroll
  for(int off=32; off; off>>=1) loc += __shfl_down(loc, off, 64);
  if((t&63)==0) red[t>>6] = loc;
  __syncthreads();
  float tot = 0.f;
  #pragma unroll
  for(int w=0;w<8;w++) tot += red[w];
  __syncthreads();
  return tot;
}

__global__ void msvl_zero(float* out){ out[0] = 0.f; }

__global__ void __launch_bounds__(1024)
msvl_main(float* x, float* circ, float* b0, float* out){
  __shared__ float2 bufs[2][BUFSZ];   // 2 x 69,632 B = 139,264 B
  __shared__ float reds[2][8];
  const int tid  = threadIdx.x;
  const int half = tid >> 9;          // which row of the pair
  const int t    = tid & 511;         // per-row thread id (identical role as before)
  const int row  = (blockIdx.x << 1) | half;

  float2* buf = bufs[half];
  float*  red = reds[half];

  float* xrow = x    + (size_t)row * NN;
  float* crow = circ + (size_t)row * NN;
  float* brow = b0   + (size_t)row * NN;

  // Padded-layout per-thread bases (iteration-invariant, 4 small ints).
  const int aS1 = t + (t>>4);
  const int a2  = (t>>8)*4352 + (t&255) + ((t&255)>>4);
  const int a3  = (t>>4)*272 + (t&15);
  const int aM  = 17*t;

  // Per-thread twiddle bases (8 scalars; redefined opaquely in-loop vs LICM).
  float s1v,c1v,s2v,c2v,s3v,c3v,psv,pcv;
  __sincosf(-6.28318530718f*(float)t/8192.f,        &s1v,&c1v);
  __sincosf(-6.28318530718f*(float)(t&255)/4096.f,  &s2v,&c2v);
  __sincosf(-6.28318530718f*(float)(t&15)/256.f,    &s3v,&c3v);
  __sincosf(-3.14159265359f*(float)t/8192.f,        &psv,&pcv);
  const float2 phstep = make_float2(0.98078528040f, -0.19509032202f);

  float breg[16];

  // --- init: b = b0 / ||b0||  (per row; precedes spectra overwrite of brow) --
  {
    float nrm = 0.f;
    #pragma unroll
    for(int j=0;j<16;j++){ float v = brow[t+512*j]; breg[j]=v; nrm = fmaf(v,v,nrm); }
    #pragma unroll
    for(int off=32; off; off>>=1) nrm += __shfl_down(nrm, off, 64);
    if((t&63)==0) red[t>>6] = nrm;
    __syncthreads();
    float tot = 0.f;
    #pragma unroll
    for(int w=0;w<8;w++) tot += red[w];
    float isc = rsqrtf(tot);
    #pragma unroll
    for(int j=0;j<16;j++) breg[j] *= isc;
  }

  // --- precompute spectra (3 forward FFTs) -> global (over input rows) ------
  {
    const float2 w1 = make_float2(c1v,s1v), w2 = make_float2(c2v,s2v), w3 = make_float2(c3v,s3v);
    float fj[16], dj[16];
    #pragma unroll
    for(int j=0;j<16;j++){
      int n = t + 512*j;
      float xn = xrow[n];
      float xr = (n==0) ? 0.f : xrow[NN - n];
      fj[j] = xn + xr;
      dj[j] = xn - xr;
    }
    // FFT(f) -> 0.5*S2e at slots aM+j
    fwd_s1_real(buf, aS1, fj, w1);
    __syncthreads();
    fwd_stage16(buf, a2, 272, w2);
    __syncthreads();
    fwd_stage16(buf, a3, 17,  w3);
    __syncthreads();
    fwd_stage_last(buf, aM);
    __syncthreads();
    float se[16];
    #pragma unroll
    for(int j=0;j<16;j++) se[j] = 0.5f * buf[aM + j].x;
    __syncthreads();
    // FFT(d*phi) -> 0.5*S2o -> brow
    {
      float2 ph = make_float2(pcv, psv);
      float2 tmp[16];
      #pragma unroll
      for(int j=0;j<16;j++){ tmp[j] = make_float2(dj[j]*ph.x, dj[j]*ph.y); ph = cmul(ph, phstep); }
      fwd_s1_cplx(buf, aS1, tmp, w1);
    }
    __syncthreads();
    fwd_stage16(buf, a2, 272, w2);
    __syncthreads();
    fwd_stage16(buf, a3, 17,  w3);
    __syncthreads();
    fwd_stage_last(buf, aM);
    __syncthreads();
    #pragma unroll
    for(int j=0;j<16;j++) brow[16*t+j] = 0.5f * buf[aM + j].x;
    __syncthreads();
    // FFT(c) -> Fc; G = Fc*(1 + i*se) -> xrow/crow
    #pragma unroll
    for(int j=0;j<16;j++) fj[j] = crow[t+512*j];
    fwd_s1_real(buf, aS1, fj, w1);
    __syncthreads();
    fwd_stage16(buf, a2, 272, w2);
    __syncthreads();
    fwd_stage16(buf, a3, 17,  w3);
    __syncthreads();
    fwd_stage_last(buf, aM);
    __syncthreads();
    if (t < 256) {
      float2* gdst = (float2*)xrow;
      #pragma unroll
      for(int j=0;j<16;j++){
        int e = 16*t + j;
        float2 fc = buf[aM + j];
        gdst[e] = make_float2(fmaf(-fc.y, se[j], fc.x), fmaf(fc.x, se[j], fc.y));
      }
    } else {
      float2* gdst = (float2*)crow;
      #pragma unroll
      for(int j=0;j<16;j++){
        int e = 16*t + j;
        float2 fc = buf[aM + j];
        gdst[e - 4096] = make_float2(fmaf(-fc.y, se[j], fc.x), fmaf(fc.x, se[j], fc.y));
      }
    }
    __syncthreads();
  }

  const float4* gptr = (t < 256) ? (const float4*)((const float2*)xrow + 16*t)
                                 : (const float4*)((const float2*)crow + (16*t - 4096));
  const float4* sptr = (const float4*)(brow + 16*t);

  // --- 100 power iterations (rolled) ----------------------------------------
  #pragma clang loop unroll(disable)
  for(int iter=0; iter<100; ++iter){
    // Opaque redefinition: kills LICM hoisting/spilling of all twiddle chains.
    asm volatile("" : "+v"(c1v), "+v"(s1v), "+v"(c2v), "+v"(s2v),
                      "+v"(c3v), "+v"(s3v), "+v"(pcv), "+v"(psv));
    const float2 w1 = make_float2(c1v,s1v), w2 = make_float2(c2v,s2v), w3 = make_float2(c3v,s3v);
    float tot = iterate<false>(buf, red, t, breg, aS1, a2, a3, aM,
                               w1, w2, w3, pcv, psv, gptr, sptr);
    float s = rsqrtf(tot);
    #pragma unroll
    for(int j=0;j<16;j++) breg[j] *= s;
  }

  // --- final matvec for sigma ------------------------------------------------
  {
    asm volatile("" : "+v"(c1v), "+v"(s1v), "+v"(c2v), "+v"(s2v),
                      "+v"(c3v), "+v"(s3v), "+v"(pcv), "+v"(psv));
    const float2 w1 = make_float2(c1v,s1v), w2 = make_float2(c2v,s2v), w3 = make_float2(c3v,s3v);
    float tot = iterate<true>(buf, red, t, breg, aS1, a2, a3, aM,
                              w1, w2, w3, pcv, psv, gptr, sptr);
    if(t == 0) atomicAdd(out, fabsf(tot) * (1.f/512.f));
  }
}

extern "C" void kernel_launch(void* const* d_in, const int* in_sizes, int n_in,
                              void* d_out, int out_size, void* d_ws, size_t ws_size,
                              hipStream_t stream) {
  float* x    = (float*)d_in[0];
  float* circ = (float*)d_in[1];
  float* b0   = (float*)d_in[2];
  float* out  = (float*)d_out;

  hipLaunchKernelGGL(msvl_zero, dim3(1), dim3(1), 0, stream, out);
  hipLaunchKernelGGL(msvl_main, dim3(ROWS/2), dim3(1024), 0, stream,
                     x, circ, b0, out);
}

// Round 6
// 6348.498 us; speedup vs baseline: 2.8052x; 2.8052x over previous
//
#include <hip/hip_runtime.h>
#include <math.h>

// 512 rows of length 8192. Power iteration b <- normalize(b - T(x)C(c)b), 100x,
// then sigma = b.(b - TCb); out = mean(|sigma|).
//
// ROUND 16 KEY CHANGE: radix-8 restructure (8192 = 2 x 8^4) at 512 threads.
// Evidence chain (r10-r15): dur == hbm_bytes/3.3TB/s every round -> kernel is
// HBM-traffic-bound on SCRATCH SPILLS. VGPR cap is allocator-chosen (512t ->
// 128, 1024t -> 64, targeting 2 blocks/CU and ignoring LDS); halving the cap
// (r15, 1024t) exactly doubled WRITE_SIZE. All cap-raising levers failed
// (launch_bounds 2nd arg r11, amdgpu_waves_per_eu r14: VGPR_Count pinned).
// => Only remaining lever: SHRINK live state under the 128 cap.
//   - Mid stages: radix-8, 2 butterflies/thread sequential -> y[8] (16 VGPRs)
//     peak instead of y[16] (32). 4 stages/half instead of 3 (+4 barriers/iter).
//   - S1 + epilogue junctions (s1_junction/s1_final/fwd_s1_*): UNCHANGED
//     512-thread structure, breg[16], q=0..7, 544q spacing, +4352 mirror.
//   - G & S2o spectra in global (L3-resident streams); LDS back to ~70KB ->
//     2 blocks/CU become possible once scratch stops blocking residency.
// Predicted: WRITE_SIZE 1.66e7 -> <1e6 KB, dur 8000 -> 2500-4500 us.
//
// Radix-8 DIF math (derived + double-checked):
//   dft8: a[k]=y[k]+y[k+4]; b[k]=(y[k]-y[k+4])*W8^{Dk},
//         W8^{D}={1,(C2,D*C2),(0,D),(-C2,D*C2)}; dft4(a)->even bins, dft4(b)->odd.
//   Output: bin j lands at y[SIG[j]], SIG={0,4,1,5,2,6,3,7} (= sigma).
//   Both fwd and inv stages store: slot j <- y[SIG[j]] (inv loads bin j from
//   slot j, times conj-twiddle^j; same network with conj W8 maps bins->time
//   at sigma layout).
//   Stage twiddle (DIF): w = W_{8*st}^{pos}; stages st=512,64,8,1:
//     wA = e^{-2pi i u/4096}, wB = e^{-2pi i (u&63)/512}, wC = e^{-2pi i (u&7)/64}.
//
// LDS padding a(e) = e + (e>>4); padded affine offsets (exact, carry-checked):
//   S1:      a = t+(t>>4) + 544q, mirror +4352
//   stage A: a = u+(u>>4) + 544k                  (e = u + 512k)
//   stage B: a = (u>>6)*544 + (u&63)+((u&63)>>4) + 68k   (e = (u>>6)*512+(u&63)+64k)
//   stage C: a = (u>>3)*68 + (u&7) + 8k + (k>>1)  (e = (u>>3)*64+(u&7)+8k)
//   mid:     a = 8u + (u>>1) + k                  (e = 8u + k)
//   half1 of any stage: +4352 (= pad(e+4096)-pad(e)).

#define NN 8192
#define NT 512
#define ROWS 512
#define BUFSZ 8704   // 8192 + 512 pad (float2)

__device__ __forceinline__ float2 cadd(float2 a, float2 b){ return make_float2(a.x+b.x, a.y+b.y); }
__device__ __forceinline__ float2 csub(float2 a, float2 b){ return make_float2(a.x-b.x, a.y-b.y); }
__device__ __forceinline__ float2 cmul(float2 a, float2 b){
  return make_float2(fmaf(a.x, b.x, -(a.y*b.y)), fmaf(a.x, b.y, a.y*b.x));
}
__device__ __forceinline__ float2 cscale(float2 a, float s){ return make_float2(a.x*s, a.y*s); }
__device__ __forceinline__ float2 conjf2(float2 a){ return make_float2(a.x, -a.y); }

static constexpr int SIG[8] = {0,4,1,5,2,6,3,7};   // bin j lives at y[SIG[j]]

template<int DIR> // DIR = -1 forward, +1 inverse
__device__ __forceinline__ void dft4(float2& a, float2& b, float2& c, float2& d){
  float2 t0=cadd(a,c), t1=csub(a,c), t2=cadd(b,d), t3=csub(b,d);
  float2 it3 = make_float2((float)(-DIR)*t3.y, (float)DIR*t3.x);
  a = cadd(t0,t2);
  c = csub(t0,t2);
  b = cadd(t1,it3);
  d = csub(t1,it3);
}

template<int DIR>
__device__ __forceinline__ void dft8i(float2 y[8]){
  const float C2 = 0.70710678119f;
  const float D  = (float)DIR;
  float2 a0=cadd(y[0],y[4]), a1=cadd(y[1],y[5]), a2=cadd(y[2],y[6]), a3=cadd(y[3],y[7]);
  float2 b0=csub(y[0],y[4]), b1=csub(y[1],y[5]), b2=csub(y[2],y[6]), b3=csub(y[3],y[7]);
  b1 = cmul(b1, make_float2(C2, D*C2));
  b2 = make_float2(-D*b2.y, D*b2.x);              // * (0, D)
  b3 = cmul(b3, make_float2(-C2, D*C2));
  dft4<DIR>(a0,a1,a2,a3);                          // even bins (natural)
  dft4<DIR>(b0,b1,b2,b3);                          // odd bins (natural)
  y[0]=a0; y[1]=a1; y[2]=a2; y[3]=a3;
  y[4]=b0; y[5]=b1; y[6]=b2; y[7]=b3;
}

// Padded offset within a stage: STEP*k (+ k>>1 for the st=8 stage).
template<int STEP, bool HK>
__device__ __forceinline__ constexpr int off8(int k){ return STEP*k + (HK ? (k>>1) : 0); }

// Forward radix-8 stage butterfly at padded base a0, per-thread twiddle w.
template<int STEP, bool HK>
__device__ __forceinline__ void fwd_stage8(float2* buf, int a0, float2 w){
  float2 y[8];
  #pragma unroll
  for(int k=0;k<8;k++) y[k] = buf[a0 + off8<STEP,HK>(k)];
  dft8i<-1>(y);
  float2 tw = make_float2(1.f,0.f);
  #pragma unroll
  for(int j=0;j<8;j++){
    buf[a0 + off8<STEP,HK>(j)] = cmul(y[SIG[j]], tw);
    tw = cmul(tw, w);
  }
}

// Inverse radix-8 stage (adjoint): load bin j from slot j * conj-tw^j,
// inverse network, store slot j <- y[SIG[j]] (time).
template<int STEP, bool HK>
__device__ __forceinline__ void inv_stage8(float2* buf, int a0, float2 w){
  float2 y[8];
  float2 tw = make_float2(1.f,0.f);
  #pragma unroll
  for(int k=0;k<8;k++){
    y[k] = cmul(buf[a0 + off8<STEP,HK>(k)], tw);
    tw = cmul(tw, w);
  }
  dft8i<1>(y);
  #pragma unroll
  for(int j=0;j<8;j++) buf[a0 + off8<STEP,HK>(j)] = y[SIG[j]];
}

// Last forward stage (precompute only): slot j <- bin j.
__device__ __forceinline__ void fwd_stage_last8(float2* buf, int aM){
  float2 y[8];
  #pragma unroll
  for(int k=0;k<8;k++) y[k] = buf[aM + k];
  dft8i<-1>(y);
  #pragma unroll
  for(int j=0;j<8;j++) buf[aM + j] = y[SIG[j]];
}

// Fused: fwd-last + complex-spectrum multiply (G, 4 float4 = 8 complex) + inv-first.
__device__ __forceinline__ void mid_junction_g8(float2* buf, int aM, const float4* gp){
  float2 y[8];
  #pragma unroll
  for(int k=0;k<8;k++) y[k] = buf[aM + k];
  dft8i<-1>(y);
  float2 z[8];
  #pragma unroll
  for(int j2=0;j2<4;j2++){
    float4 g = gp[j2];
    z[2*j2]   = cmul(y[SIG[2*j2]],   make_float2(g.x, g.y));
    z[2*j2+1] = cmul(y[SIG[2*j2+1]], make_float2(g.z, g.w));
  }
  dft8i<1>(z);
  #pragma unroll
  for(int k=0;k<8;k++) buf[aM + k] = z[SIG[k]];
}

// Fused: fwd-last + real-spectrum multiply (2 float4 = 8 reals) + inv-first.
__device__ __forceinline__ void mid_junction_s8(float2* buf, int aM, const float4* sp){
  float2 y[8];
  #pragma unroll
  for(int k=0;k<8;k++) y[k] = buf[aM + k];
  dft8i<-1>(y);
  float2 z[8];
  float4 s0 = sp[0], s1 = sp[1];
  z[0] = cscale(y[SIG[0]], s0.x);
  z[1] = cscale(y[SIG[1]], s0.y);
  z[2] = cscale(y[SIG[2]], s0.z);
  z[3] = cscale(y[SIG[3]], s0.w);
  z[4] = cscale(y[SIG[4]], s1.x);
  z[5] = cscale(y[SIG[5]], s1.y);
  z[6] = cscale(y[SIG[6]], s1.z);
  z[7] = cscale(y[SIG[7]], s1.w);
  dft8i<1>(z);
  #pragma unroll
  for(int k=0;k<8;k++) buf[aM + k] = z[SIG[k]];
}

// ---- S1 (radix-2) + epilogues: UNCHANGED 512-thread structure --------------

__device__ __forceinline__ void fwd_s1_real(float2* buf, int aS1, const float b[16], float2 w1){
  float2 tw = w1;
  const float2 step = make_float2(0.92387953251f, -0.38268343236f); // e^{-i pi/8}
  #pragma unroll
  for(int q=0;q<8;q++){
    int a = aS1 + 544*q;
    float d = b[q] - b[q+8];
    buf[a]        = make_float2(b[q] + b[q+8], 0.f);
    buf[a + 4352] = make_float2(d*tw.x, d*tw.y);
    tw = cmul(tw, step);
  }
}

__device__ __forceinline__ void fwd_s1_cplx(float2* buf, int aS1, const float2 in[16], float2 w1){
  float2 tw = w1;
  const float2 step = make_float2(0.92387953251f, -0.38268343236f);
  #pragma unroll
  for(int q=0;q<8;q++){
    int a = aS1 + 544*q;
    buf[a]        = cadd(in[q], in[q+8]);
    buf[a + 4352] = cmul(csub(in[q], in[q+8]), tw);
    tw = cmul(tw, step);
  }
}

template<bool SIGMA>
__device__ __forceinline__ void s1_junction(float2* buf, int aS1, float breg[16], float& loc,
                                            float2 w1, float pc, float ps, float sc1){
  float2 twi = conjf2(w1), twf = w1;
  const float2 stepi = make_float2(0.92387953251f,  0.38268343236f);
  const float2 stepf = make_float2(0.92387953251f, -0.38268343236f);
  float2 ph = make_float2(pc, ps);
  const float2 phstep = make_float2(0.98078528040f, -0.19509032202f); // e^{-i pi/16}
  #pragma unroll
  for(int q=0;q<8;q++){
    int a = aS1 + 544*q;
    float2 z0 = buf[a];
    float2 z1 = cmul(buf[a + 4352], twi);
    float2 zn = cscale(cadd(z0,z1), sc1);
    float2 zm = cscale(csub(z0,z1), sc1);
    if (SIGMA) {
      loc += breg[q]*(breg[q]-zn.y) + breg[q+8]*(breg[q+8]-zm.y);
    } else {
      breg[q]   -= zn.y;
      breg[q+8] -= zm.y;
    }
    float2 vn = make_float2(zn.x*ph.x,  zn.x*ph.y);
    float2 vm = make_float2(zm.x*ph.y, -zm.x*ph.x);
    buf[a]        = cadd(vn, vm);
    buf[a + 4352] = cmul(csub(vn, vm), twf);
    twi = cmul(twi, stepi); twf = cmul(twf, stepf); ph = cmul(ph, phstep);
  }
}

template<bool SIGMA>
__device__ __forceinline__ void s1_final(float2* buf, int aS1, float breg[16], float& loc,
                                         float2 w1, float pc, float ps, float sc2){
  float2 twi = conjf2(w1);
  const float2 stepi = make_float2(0.92387953251f, 0.38268343236f);
  float2 ph = make_float2(pc, ps);
  const float2 phstep = make_float2(0.98078528040f, -0.19509032202f);
  #pragma unroll
  for(int q=0;q<8;q++){
    int a = aS1 + 544*q;
    float2 z0 = buf[a];
    float2 z1 = cmul(buf[a + 4352], twi);
    float2 yn = cscale(cadd(z0,z1), sc2);
    float2 ym = cscale(csub(z0,z1), sc2);
    float qn = fmaf(ph.x, yn.x,  ph.y*yn.y);
    float qm = fmaf(ph.y, ym.x, -ph.x*ym.y);
    if (SIGMA) {
      loc -= breg[q]*qn + breg[q+8]*qm;
    } else {
      float bn = breg[q]   - qn; breg[q]   = bn; loc = fmaf(bn,bn,loc);
      bn       = breg[q+8] - qm; breg[q+8] = bn; loc = fmaf(bn,bn,loc);
    }
    twi = cmul(twi, stepi); ph = cmul(ph, phstep);
  }
}

// One full iteration (4 FFT passes, radix-8 mid stages x2 halves) -> tot.
template<bool SIGMA>
__device__ __forceinline__ float iterate(float2* buf, float* red, int t, float breg[16],
                                         int aS1, int aB, int aC, int aM8,
                                         float2 w1, float2 wA, float2 wB, float2 wC,
                                         float pc, float ps,
                                         const float4* gp0, const float4* gp1,
                                         const float4* sp0, const float4* sp1){
  const float sc1 = 1.f/8192.f, sc2 = 1.f/8192.f;
  float loc = 0.f;

  fwd_s1_real(buf, aS1, breg, w1);
  __syncthreads();
  fwd_stage8<544,false>(buf, aS1,        wA);
  fwd_stage8<544,false>(buf, aS1 + 4352, wA);
  __syncthreads();
  fwd_stage8<68,false>(buf, aB,        wB);
  fwd_stage8<68,false>(buf, aB + 4352, wB);
  __syncthreads();
  fwd_stage8<8,true>(buf, aC,        wC);
  fwd_stage8<8,true>(buf, aC + 4352, wC);
  __syncthreads();
  mid_junction_g8(buf, aM8,        gp0);
  mid_junction_g8(buf, aM8 + 4352, gp1);
  __syncthreads();
  inv_stage8<8,true>(buf, aC,        conjf2(wC));
  inv_stage8<8,true>(buf, aC + 4352, conjf2(wC));
  __syncthreads();
  inv_stage8<68,false>(buf, aB,        conjf2(wB));
  inv_stage8<68,false>(buf, aB + 4352, conjf2(wB));
  __syncthreads();
  inv_stage8<544,false>(buf, aS1,        conjf2(wA));
  inv_stage8<544,false>(buf, aS1 + 4352, conjf2(wA));
  __syncthreads();
  s1_junction<SIGMA>(buf, aS1, breg, loc, w1, pc, ps, sc1);
  __syncthreads();
  fwd_stage8<544,false>(buf, aS1,        wA);
  fwd_stage8<544,false>(buf, aS1 + 4352, wA);
  __syncthreads();
  fwd_stage8<68,false>(buf, aB,        wB);
  fwd_stage8<68,false>(buf, aB + 4352, wB);
  __syncthreads();
  fwd_stage8<8,true>(buf, aC,        wC);
  fwd_stage8<8,true>(buf, aC + 4352, wC);
  __syncthreads();
  mid_junction_s8(buf, aM8,        sp0);
  mid_junction_s8(buf, aM8 + 4352, sp1);
  __syncthreads();
  inv_stage8<8,true>(buf, aC,        conjf2(wC));
  inv_stage8<8,true>(buf, aC + 4352, conjf2(wC));
  __syncthreads();
  inv_stage8<68,false>(buf, aB,        conjf2(wB));
  inv_stage8<68,false>(buf, aB + 4352, conjf2(wB));
  __syncthreads();
  inv_stage8<544,false>(buf, aS1,        conjf2(wA));
  inv_stage8<544,false>(buf, aS1 + 4352, conjf2(wA));
  __syncthreads();
  s1_final<SIGMA>(buf, aS1, breg, loc, w1, pc, ps, sc2);

  __syncthreads();
  #pragma unroll
  for(int off=32; off; off>>=1) loc += __shfl_down(loc, off, 64);
  if((t&63)==0) red[t>>6] = loc;
  __syncthreads();
  float tot = 0.f;
  #pragma unroll
  for(int w=0;w<8;w++) tot += red[w];
  __syncthreads();
  return tot;
}

__global__ void msvl_zero(float* out){ out[0] = 0.f; }

__global__ void __launch_bounds__(512)
msvl_main(float* x, float* circ, float* b0, float* out){
  __shared__ float2 buf[BUFSZ];   // 69,632 B -> 2 blocks/CU (once scratch-free)
  __shared__ float red[8];
  const int t = threadIdx.x;
  const int row = blockIdx.x;

  float* xrow = x    + (size_t)row * NN;
  float* crow = circ + (size_t)row * NN;
  float* brow = b0   + (size_t)row * NN;

  // Padded per-thread bases (iteration-invariant).
  const int aS1 = t + (t>>4);                              // also stage-A base (e = t)
  const int aB  = (t>>6)*544 + (t&63) + ((t&63)>>4);       // stage B
  const int aC  = (t>>3)*68 + (t&7);                       // stage C
  const int aM8 = 8*t + (t>>1);                            // mid blocks (e = 8t)

  // Per-thread twiddle scalars (10, redefined opaquely in-loop vs LICM).
  float s1v,c1v,sAv,cAv,sBv,cBv,sCv,cCv,psv,pcv;
  __sincosf(-6.28318530718f*(float)t/8192.f,       &s1v,&c1v);   // w1 (S1)
  __sincosf(-6.28318530718f*(float)t/4096.f,       &sAv,&cAv);   // wA (st=512)
  __sincosf(-6.28318530718f*(float)(t&63)/512.f,   &sBv,&cBv);   // wB (st=64)
  __sincosf(-6.28318530718f*(float)(t&7)/64.f,     &sCv,&cCv);   // wC (st=8)
  __sincosf(-3.14159265359f*(float)t/8192.f,       &psv,&pcv);   // phi
  const float2 phstep = make_float2(0.98078528040f, -0.19509032202f);

  float breg[16];

  // --- init: b = b0 / ||b0||  (precedes spectra overwrite of brow) ----------
  {
    float nrm = 0.f;
    #pragma unroll
    for(int j=0;j<16;j++){ float v = brow[t+512*j]; breg[j]=v; nrm = fmaf(v,v,nrm); }
    #pragma unroll
    for(int off=32; off; off>>=1) nrm += __shfl_down(nrm, off, 64);
    if((t&63)==0) red[t>>6] = nrm;
    __syncthreads();
    float tot = 0.f;
    #pragma unroll
    for(int w=0;w<8;w++) tot += red[w];
    float isc = rsqrtf(tot);
    #pragma unroll
    for(int j=0;j<16;j++) breg[j] *= isc;
  }

  // --- precompute spectra (3 forward FFTs) -> global ------------------------
  // Bin layout per thread: slots j=0..7 of block (half0, t) and (half1, t):
  //   G (complex): gx[8t+j] (xrow), gc[8t+j] (crow);  S2o (real): brow[8t+j], brow[4096+8t+j].
  {
    const float2 w1 = make_float2(c1v,s1v), wA = make_float2(cAv,sAv),
                 wB = make_float2(cBv,sBv), wC = make_float2(cCv,sCv);
    float fj[16], dj[16];
    #pragma unroll
    for(int j=0;j<16;j++){
      int n = t + 512*j;
      float xn = xrow[n];
      float xr = (n==0) ? 0.f : xrow[NN - n];
      fj[j] = xn + xr;
      dj[j] = xn - xr;
    }
    // FFT(f) -> 0.5*S2e (register se[16])
    fwd_s1_real(buf, aS1, fj, w1);
    __syncthreads();
    fwd_stage8<544,false>(buf, aS1, wA); fwd_stage8<544,false>(buf, aS1+4352, wA);
    __syncthreads();
    fwd_stage8<68,false>(buf, aB, wB);   fwd_stage8<68,false>(buf, aB+4352, wB);
    __syncthreads();
    fwd_stage8<8,true>(buf, aC, wC);     fwd_stage8<8,true>(buf, aC+4352, wC);
    __syncthreads();
    fwd_stage_last8(buf, aM8);           fwd_stage_last8(buf, aM8+4352);
    __syncthreads();
    float se[16];
    #pragma unroll
    for(int j=0;j<8;j++){ se[j] = 0.5f * buf[aM8 + j].x; se[8+j] = 0.5f * buf[aM8 + 4352 + j].x; }
    __syncthreads();
    // FFT(d*phi) -> 0.5*S2o -> brow
    {
      float2 ph = make_float2(pcv, psv);
      float2 tmp[16];
      #pragma unroll
      for(int j=0;j<16;j++){ tmp[j] = make_float2(dj[j]*ph.x, dj[j]*ph.y); ph = cmul(ph, phstep); }
      fwd_s1_cplx(buf, aS1, tmp, w1);
    }
    __syncthreads();
    fwd_stage8<544,false>(buf, aS1, wA); fwd_stage8<544,false>(buf, aS1+4352, wA);
    __syncthreads();
    fwd_stage8<68,false>(buf, aB, wB);   fwd_stage8<68,false>(buf, aB+4352, wB);
    __syncthreads();
    fwd_stage8<8,true>(buf, aC, wC);     fwd_stage8<8,true>(buf, aC+4352, wC);
    __syncthreads();
    fwd_stage_last8(buf, aM8);           fwd_stage_last8(buf, aM8+4352);
    __syncthreads();
    #pragma unroll
    for(int j=0;j<8;j++){
      brow[8*t + j]        = 0.5f * buf[aM8 + j].x;
      brow[4096 + 8*t + j] = 0.5f * buf[aM8 + 4352 + j].x;
    }
    __syncthreads();
    // FFT(c) -> Fc; G = Fc*(1 + i*se) -> gx (xrow) / gc (crow)
    #pragma unroll
    for(int j=0;j<16;j++) fj[j] = crow[t+512*j];
    fwd_s1_real(buf, aS1, fj, w1);
    __syncthreads();
    fwd_stage8<544,false>(buf, aS1, wA); fwd_stage8<544,false>(buf, aS1+4352, wA);
    __syncthreads();
    fwd_stage8<68,false>(buf, aB, wB);   fwd_stage8<68,false>(buf, aB+4352, wB);
    __syncthreads();
    fwd_stage8<8,true>(buf, aC, wC);     fwd_stage8<8,true>(buf, aC+4352, wC);
    __syncthreads();
    fwd_stage_last8(buf, aM8);           fwd_stage_last8(buf, aM8+4352);
    __syncthreads();
    {
      float2* gx = (float2*)xrow;
      float2* gc = (float2*)crow;
      #pragma unroll
      for(int j=0;j<8;j++){
        float2 f0 = buf[aM8 + j];
        float2 f1 = buf[aM8 + 4352 + j];
        gx[8*t + j] = make_float2(fmaf(-f0.y, se[j],   f0.x), fmaf(f0.x, se[j],   f0.y));
        gc[8*t + j] = make_float2(fmaf(-f1.y, se[8+j], f1.x), fmaf(f1.x, se[8+j], f1.y));
      }
    }
    __syncthreads();
  }

  const float4* gp0 = (const float4*)((const float2*)xrow + 8*t);
  const float4* gp1 = (const float4*)((const float2*)crow + 8*t);
  const float4* sp0 = (const float4*)(brow + 8*t);
  const float4* sp1 = (const float4*)(brow + 4096 + 8*t);

  // --- 100 power iterations (rolled) ----------------------------------------
  #pragma clang loop unroll(disable)
  for(int iter=0; iter<100; ++iter){
    // Opaque redefinition: kills LICM hoisting/spilling of all twiddle chains.
    asm volatile("" : "+v"(c1v), "+v"(s1v), "+v"(cAv), "+v"(sAv),
                      "+v"(cBv), "+v"(sBv), "+v"(cCv), "+v"(sCv),
                      "+v"(pcv), "+v"(psv));
    const float2 w1 = make_float2(c1v,s1v), wA = make_float2(cAv,sAv),
                 wB = make_float2(cBv,sBv), wC = make_float2(cCv,sCv);
    float tot = iterate<false>(buf, red, t, breg, aS1, aB, aC, aM8,
                               w1, wA, wB, wC, pcv, psv, gp0, gp1, sp0, sp1);
    float s = rsqrtf(tot);
    #pragma unroll
    for(int j=0;j<16;j++) breg[j] *= s;
  }

  // --- final matvec for sigma ------------------------------------------------
  {
    asm volatile("" : "+v"(c1v), "+v"(s1v), "+v"(cAv), "+v"(sAv),
                      "+v"(cBv), "+v"(sBv), "+v"(cCv), "+v"(sCv),
                      "+v"(pcv), "+v"(psv));
    const float2 w1 = make_float2(c1v,s1v), wA = make_float2(cAv,sAv),
                 wB = make_float2(cBv,sBv), wC = make_float2(cCv,sCv);
    float tot = iterate<true>(buf, red, t, breg, aS1, aB, aC, aM8,
                              w1, wA, wB, wC, pcv, psv, gp0, gp1, sp0, sp1);
    if(t == 0) atomicAdd(out, fabsf(tot) * (1.f/512.f));
  }
}

extern "C" void kernel_launch(void* const* d_in, const int* in_sizes, int n_in,
                              void* d_out, int out_size, void* d_ws, size_t ws_size,
                              hipStream_t stream) {
  float* x    = (float*)d_in[0];
  float* circ = (float*)d_in[1];
  float* b0   = (float*)d_in[2];
  float* out  = (float*)d_out;

  hipLaunchKernelGGL(msvl_zero, dim3(1), dim3(1), 0, stream, out);
  hipLaunchKernelGGL(msvl_main, dim3(ROWS), dim3(NT), 0, stream,
                     x, circ, b0, out);
}

// Round 7
// 4431.214 us; speedup vs baseline: 4.0189x; 1.4327x over previous
//
#include <hip/hip_runtime.h>
#include <math.h>

// 512 rows of length 8192. Power iteration b <- normalize(b - T(x)C(c)b), 100x,
// then sigma = b.(b - TCb); out = mean(|sigma|).
//
// ROUND 17 KEY CHANGE: serialize the per-stage half-pairs. r16 (radix-8)
// halved the spill round-trip (WRITE 16.6->8.5 GB, dur 8.0->6.4 ms) but
// VGPR_Count stayed pinned at exactly 128 -> allocator still over budget.
// Diagnosis: each stage is a back-to-back PAIR of calls (half0 at base,
// half1 at base+4352) with no barrier between; the scheduler interleaves
// them for ILP -> 2x y[8] + 2x twiddle chains + (for the junction pair) all
// 8 hoisted float4 spectrum loads live at once ~= 140 regs > 128 -> spill.
// Fix: each pair becomes a trip-count-2 loop with
//   #pragma clang loop unroll(disable)
// (AMDGPU backend has no modulo scheduler -> rolled loop hard-caps pressure
// at one call's worth ~80 regs). Junction pointers via ternary, not array
// (runtime-indexed arrays -> scratch). Everything else identical to r16.
// Predicted: VGPR < 128 (first time off the pin), WRITE < 1e6 KB,
// occupancy -> ~45% (2 blocks/CU), dur -> 3.5-4.8 ms.
//
// Radix-8 DIF math (verified r16, absmax 0):
//   dft8: a[k]=y[k]+y[k+4]; b[k]=(y[k]-y[k+4])*W8^{Dk},
//         W8^{D}={1,(C2,D*C2),(0,D),(-C2,D*C2)}; dft4(a)->even, dft4(b)->odd.
//   Bin j lands at y[SIG[j]], SIG={0,4,1,5,2,6,3,7}; both directions store
//   slot j <- y[SIG[j]].
//   Twiddles: wA = e^{-2pi i t/4096}, wB = e^{-2pi i (t&63)/512},
//             wC = e^{-2pi i (t&7)/64}.
//
// LDS padding a(e) = e + (e>>4); padded affine offsets (carry-checked):
//   S1:      a = t+(t>>4) + 544q, mirror +4352
//   stage A: a = aS1 + 544k
//   stage B: a = (t>>6)*544 + (t&63)+((t&63)>>4) + 68k
//   stage C: a = (t>>3)*68 + (t&7) + 8k + (k>>1)
//   mid:     a = 8t + (t>>1) + k
//   half1 of any stage: +4352 (= pad(e+4096)-pad(e)).

#define NN 8192
#define NT 512
#define ROWS 512
#define BUFSZ 8704   // 8192 + 512 pad (float2)

__device__ __forceinline__ float2 cadd(float2 a, float2 b){ return make_float2(a.x+b.x, a.y+b.y); }
__device__ __forceinline__ float2 csub(float2 a, float2 b){ return make_float2(a.x-b.x, a.y-b.y); }
__device__ __forceinline__ float2 cmul(float2 a, float2 b){
  return make_float2(fmaf(a.x, b.x, -(a.y*b.y)), fmaf(a.x, b.y, a.y*b.x));
}
__device__ __forceinline__ float2 cscale(float2 a, float s){ return make_float2(a.x*s, a.y*s); }
__device__ __forceinline__ float2 conjf2(float2 a){ return make_float2(a.x, -a.y); }

static constexpr int SIG[8] = {0,4,1,5,2,6,3,7};   // bin j lives at y[SIG[j]]

template<int DIR> // DIR = -1 forward, +1 inverse
__device__ __forceinline__ void dft4(float2& a, float2& b, float2& c, float2& d){
  float2 t0=cadd(a,c), t1=csub(a,c), t2=cadd(b,d), t3=csub(b,d);
  float2 it3 = make_float2((float)(-DIR)*t3.y, (float)DIR*t3.x);
  a = cadd(t0,t2);
  c = csub(t0,t2);
  b = cadd(t1,it3);
  d = csub(t1,it3);
}

template<int DIR>
__device__ __forceinline__ void dft8i(float2 y[8]){
  const float C2 = 0.70710678119f;
  const float D  = (float)DIR;
  float2 a0=cadd(y[0],y[4]), a1=cadd(y[1],y[5]), a2=cadd(y[2],y[6]), a3=cadd(y[3],y[7]);
  float2 b0=csub(y[0],y[4]), b1=csub(y[1],y[5]), b2=csub(y[2],y[6]), b3=csub(y[3],y[7]);
  b1 = cmul(b1, make_float2(C2, D*C2));
  b2 = make_float2(-D*b2.y, D*b2.x);              // * (0, D)
  b3 = cmul(b3, make_float2(-C2, D*C2));
  dft4<DIR>(a0,a1,a2,a3);                          // even bins (natural)
  dft4<DIR>(b0,b1,b2,b3);                          // odd bins (natural)
  y[0]=a0; y[1]=a1; y[2]=a2; y[3]=a3;
  y[4]=b0; y[5]=b1; y[6]=b2; y[7]=b3;
}

// Padded offset within a stage: STEP*k (+ k>>1 for the st=8 stage).
template<int STEP, bool HK>
__device__ __forceinline__ constexpr int off8(int k){ return STEP*k + (HK ? (k>>1) : 0); }

// Forward radix-8 stage butterfly at padded base a0, per-thread twiddle w.
template<int STEP, bool HK>
__device__ __forceinline__ void fwd_stage8(float2* buf, int a0, float2 w){
  float2 y[8];
  #pragma unroll
  for(int k=0;k<8;k++) y[k] = buf[a0 + off8<STEP,HK>(k)];
  dft8i<-1>(y);
  float2 tw = make_float2(1.f,0.f);
  #pragma unroll
  for(int j=0;j<8;j++){
    buf[a0 + off8<STEP,HK>(j)] = cmul(y[SIG[j]], tw);
    tw = cmul(tw, w);
  }
}

// Inverse radix-8 stage (adjoint): load bin j from slot j * conj-tw^j,
// inverse network, store slot j <- y[SIG[j]] (time).
template<int STEP, bool HK>
__device__ __forceinline__ void inv_stage8(float2* buf, int a0, float2 w){
  float2 y[8];
  float2 tw = make_float2(1.f,0.f);
  #pragma unroll
  for(int k=0;k<8;k++){
    y[k] = cmul(buf[a0 + off8<STEP,HK>(k)], tw);
    tw = cmul(tw, w);
  }
  dft8i<1>(y);
  #pragma unroll
  for(int j=0;j<8;j++) buf[a0 + off8<STEP,HK>(j)] = y[SIG[j]];
}

// Last forward stage (precompute only): slot j <- bin j.
__device__ __forceinline__ void fwd_stage_last8(float2* buf, int aM){
  float2 y[8];
  #pragma unroll
  for(int k=0;k<8;k++) y[k] = buf[aM + k];
  dft8i<-1>(y);
  #pragma unroll
  for(int j=0;j<8;j++) buf[aM + j] = y[SIG[j]];
}

// Fused: fwd-last + complex-spectrum multiply (G, 4 float4 = 8 complex) + inv-first.
__device__ __forceinline__ void mid_junction_g8(float2* buf, int aM, const float4* gp){
  float2 y[8];
  #pragma unroll
  for(int k=0;k<8;k++) y[k] = buf[aM + k];
  dft8i<-1>(y);
  float2 z[8];
  #pragma unroll
  for(int j2=0;j2<4;j2++){
    float4 g = gp[j2];
    z[2*j2]   = cmul(y[SIG[2*j2]],   make_float2(g.x, g.y));
    z[2*j2+1] = cmul(y[SIG[2*j2+1]], make_float2(g.z, g.w));
  }
  dft8i<1>(z);
  #pragma unroll
  for(int k=0;k<8;k++) buf[aM + k] = z[SIG[k]];
}

// Fused: fwd-last + real-spectrum multiply (2 float4 = 8 reals) + inv-first.
__device__ __forceinline__ void mid_junction_s8(float2* buf, int aM, const float4* sp){
  float2 y[8];
  #pragma unroll
  for(int k=0;k<8;k++) y[k] = buf[aM + k];
  dft8i<-1>(y);
  float2 z[8];
  float4 s0 = sp[0], s1 = sp[1];
  z[0] = cscale(y[SIG[0]], s0.x);
  z[1] = cscale(y[SIG[1]], s0.y);
  z[2] = cscale(y[SIG[2]], s0.z);
  z[3] = cscale(y[SIG[3]], s0.w);
  z[4] = cscale(y[SIG[4]], s1.x);
  z[5] = cscale(y[SIG[5]], s1.y);
  z[6] = cscale(y[SIG[6]], s1.z);
  z[7] = cscale(y[SIG[7]], s1.w);
  dft8i<1>(z);
  #pragma unroll
  for(int k=0;k<8;k++) buf[aM + k] = z[SIG[k]];
}

// ---- S1 (radix-2) + epilogues: UNCHANGED 512-thread structure --------------

__device__ __forceinline__ void fwd_s1_real(float2* buf, int aS1, const float b[16], float2 w1){
  float2 tw = w1;
  const float2 step = make_float2(0.92387953251f, -0.38268343236f); // e^{-i pi/8}
  #pragma unroll
  for(int q=0;q<8;q++){
    int a = aS1 + 544*q;
    float d = b[q] - b[q+8];
    buf[a]        = make_float2(b[q] + b[q+8], 0.f);
    buf[a + 4352] = make_float2(d*tw.x, d*tw.y);
    tw = cmul(tw, step);
  }
}

__device__ __forceinline__ void fwd_s1_cplx(float2* buf, int aS1, const float2 in[16], float2 w1){
  float2 tw = w1;
  const float2 step = make_float2(0.92387953251f, -0.38268343236f);
  #pragma unroll
  for(int q=0;q<8;q++){
    int a = aS1 + 544*q;
    buf[a]        = cadd(in[q], in[q+8]);
    buf[a + 4352] = cmul(csub(in[q], in[q+8]), tw);
    tw = cmul(tw, step);
  }
}

template<bool SIGMA>
__device__ __forceinline__ void s1_junction(float2* buf, int aS1, float breg[16], float& loc,
                                            float2 w1, float pc, float ps, float sc1){
  float2 twi = conjf2(w1), twf = w1;
  const float2 stepi = make_float2(0.92387953251f,  0.38268343236f);
  const float2 stepf = make_float2(0.92387953251f, -0.38268343236f);
  float2 ph = make_float2(pc, ps);
  const float2 phstep = make_float2(0.98078528040f, -0.19509032202f); // e^{-i pi/16}
  #pragma unroll
  for(int q=0;q<8;q++){
    int a = aS1 + 544*q;
    float2 z0 = buf[a];
    float2 z1 = cmul(buf[a + 4352], twi);
    float2 zn = cscale(cadd(z0,z1), sc1);
    float2 zm = cscale(csub(z0,z1), sc1);
    if (SIGMA) {
      loc += breg[q]*(breg[q]-zn.y) + breg[q+8]*(breg[q+8]-zm.y);
    } else {
      breg[q]   -= zn.y;
      breg[q+8] -= zm.y;
    }
    float2 vn = make_float2(zn.x*ph.x,  zn.x*ph.y);
    float2 vm = make_float2(zm.x*ph.y, -zm.x*ph.x);
    buf[a]        = cadd(vn, vm);
    buf[a + 4352] = cmul(csub(vn, vm), twf);
    twi = cmul(twi, stepi); twf = cmul(twf, stepf); ph = cmul(ph, phstep);
  }
}

template<bool SIGMA>
__device__ __forceinline__ void s1_final(float2* buf, int aS1, float breg[16], float& loc,
                                         float2 w1, float pc, float ps, float sc2){
  float2 twi = conjf2(w1);
  const float2 stepi = make_float2(0.92387953251f, 0.38268343236f);
  float2 ph = make_float2(pc, ps);
  const float2 phstep = make_float2(0.98078528040f, -0.19509032202f);
  #pragma unroll
  for(int q=0;q<8;q++){
    int a = aS1 + 544*q;
    float2 z0 = buf[a];
    float2 z1 = cmul(buf[a + 4352], twi);
    float2 yn = cscale(cadd(z0,z1), sc2);
    float2 ym = cscale(csub(z0,z1), sc2);
    float qn = fmaf(ph.x, yn.x,  ph.y*yn.y);
    float qm = fmaf(ph.y, ym.x, -ph.x*ym.y);
    if (SIGMA) {
      loc -= breg[q]*qn + breg[q+8]*qm;
    } else {
      float bn = breg[q]   - qn; breg[q]   = bn; loc = fmaf(bn,bn,loc);
      bn       = breg[q+8] - qm; breg[q+8] = bn; loc = fmaf(bn,bn,loc);
    }
    twi = cmul(twi, stepi); ph = cmul(ph, phstep);
  }
}

// One full iteration (4 FFT passes, radix-8 mid stages, serialized halves).
template<bool SIGMA>
__device__ __forceinline__ float iterate(float2* buf, float* red, int t, float breg[16],
                                         int aS1, int aB, int aC, int aM8,
                                         float2 w1, float2 wA, float2 wB, float2 wC,
                                         float pc, float ps,
                                         const float4* gp0, const float4* gp1,
                                         const float4* sp0, const float4* sp1){
  const float sc1 = 1.f/8192.f, sc2 = 1.f/8192.f;
  float loc = 0.f;

  fwd_s1_real(buf, aS1, breg, w1);
  __syncthreads();
  #pragma clang loop unroll(disable)
  for(int h=0; h<2; ++h) fwd_stage8<544,false>(buf, aS1 + 4352*h, wA);
  __syncthreads();
  #pragma clang loop unroll(disable)
  for(int h=0; h<2; ++h) fwd_stage8<68,false>(buf, aB + 4352*h, wB);
  __syncthreads();
  #pragma clang loop unroll(disable)
  for(int h=0; h<2; ++h) fwd_stage8<8,true>(buf, aC + 4352*h, wC);
  __syncthreads();
  #pragma clang loop unroll(disable)
  for(int h=0; h<2; ++h) mid_junction_g8(buf, aM8 + 4352*h, h ? gp1 : gp0);
  __syncthreads();
  #pragma clang loop unroll(disable)
  for(int h=0; h<2; ++h) inv_stage8<8,true>(buf, aC + 4352*h, conjf2(wC));
  __syncthreads();
  #pragma clang loop unroll(disable)
  for(int h=0; h<2; ++h) inv_stage8<68,false>(buf, aB + 4352*h, conjf2(wB));
  __syncthreads();
  #pragma clang loop unroll(disable)
  for(int h=0; h<2; ++h) inv_stage8<544,false>(buf, aS1 + 4352*h, conjf2(wA));
  __syncthreads();
  s1_junction<SIGMA>(buf, aS1, breg, loc, w1, pc, ps, sc1);
  __syncthreads();
  #pragma clang loop unroll(disable)
  for(int h=0; h<2; ++h) fwd_stage8<544,false>(buf, aS1 + 4352*h, wA);
  __syncthreads();
  #pragma clang loop unroll(disable)
  for(int h=0; h<2; ++h) fwd_stage8<68,false>(buf, aB + 4352*h, wB);
  __syncthreads();
  #pragma clang loop unroll(disable)
  for(int h=0; h<2; ++h) fwd_stage8<8,true>(buf, aC + 4352*h, wC);
  __syncthreads();
  #pragma clang loop unroll(disable)
  for(int h=0; h<2; ++h) mid_junction_s8(buf, aM8 + 4352*h, h ? sp1 : sp0);
  __syncthreads();
  #pragma clang loop unroll(disable)
  for(int h=0; h<2; ++h) inv_stage8<8,true>(buf, aC + 4352*h, conjf2(wC));
  __syncthreads();
  #pragma clang loop unroll(disable)
  for(int h=0; h<2; ++h) inv_stage8<68,false>(buf, aB + 4352*h, conjf2(wB));
  __syncthreads();
  #pragma clang loop unroll(disable)
  for(int h=0; h<2; ++h) inv_stage8<544,false>(buf, aS1 + 4352*h, conjf2(wA));
  __syncthreads();
  s1_final<SIGMA>(buf, aS1, breg, loc, w1, pc, ps, sc2);

  __syncthreads();
  #pragma unroll
  for(int off=32; off; off>>=1) loc += __shfl_down(loc, off, 64);
  if((t&63)==0) red[t>>6] = loc;
  __syncthreads();
  float tot = 0.f;
  #pragma unroll
  for(int w=0;w<8;w++) tot += red[w];
  __syncthreads();
  return tot;
}

__global__ void msvl_zero(float* out){ out[0] = 0.f; }

__global__ void __launch_bounds__(512)
msvl_main(float* x, float* circ, float* b0, float* out){
  __shared__ float2 buf[BUFSZ];   // 69,632 B -> 2 blocks/CU once scratch-free
  __shared__ float red[8];
  const int t = threadIdx.x;
  const int row = blockIdx.x;

  float* xrow = x    + (size_t)row * NN;
  float* crow = circ + (size_t)row * NN;
  float* brow = b0   + (size_t)row * NN;

  // Padded per-thread bases (iteration-invariant).
  const int aS1 = t + (t>>4);                              // also stage-A base
  const int aB  = (t>>6)*544 + (t&63) + ((t&63)>>4);       // stage B
  const int aC  = (t>>3)*68 + (t&7);                       // stage C
  const int aM8 = 8*t + (t>>1);                            // mid blocks

  // Per-thread twiddle scalars (10, redefined opaquely in-loop vs LICM).
  float s1v,c1v,sAv,cAv,sBv,cBv,sCv,cCv,psv,pcv;
  __sincosf(-6.28318530718f*(float)t/8192.f,       &s1v,&c1v);   // w1 (S1)
  __sincosf(-6.28318530718f*(float)t/4096.f,       &sAv,&cAv);   // wA (st=512)
  __sincosf(-6.28318530718f*(float)(t&63)/512.f,   &sBv,&cBv);   // wB (st=64)
  __sincosf(-6.28318530718f*(float)(t&7)/64.f,     &sCv,&cCv);   // wC (st=8)
  __sincosf(-3.14159265359f*(float)t/8192.f,       &psv,&pcv);   // phi
  const float2 phstep = make_float2(0.98078528040f, -0.19509032202f);

  float breg[16];

  // --- init: b = b0 / ||b0||  (precedes spectra overwrite of brow) ----------
  {
    float nrm = 0.f;
    #pragma unroll
    for(int j=0;j<16;j++){ float v = brow[t+512*j]; breg[j]=v; nrm = fmaf(v,v,nrm); }
    #pragma unroll
    for(int off=32; off; off>>=1) nrm += __shfl_down(nrm, off, 64);
    if((t&63)==0) red[t>>6] = nrm;
    __syncthreads();
    float tot = 0.f;
    #pragma unroll
    for(int w=0;w<8;w++) tot += red[w];
    float isc = rsqrtf(tot);
    #pragma unroll
    for(int j=0;j<16;j++) breg[j] *= isc;
  }

  // --- precompute spectra (3 forward FFTs) -> global ------------------------
  // Bin layout per thread: slots j=0..7 of blocks (half0,t),(half1,t):
  //   G: gx[8t+j] (xrow), gc[8t+j] (crow);  S2o: brow[8t+j], brow[4096+8t+j].
  {
    const float2 w1 = make_float2(c1v,s1v), wA = make_float2(cAv,sAv),
                 wB = make_float2(cBv,sBv), wC = make_float2(cCv,sCv);
    float fj[16], dj[16];
    #pragma unroll
    for(int j=0;j<16;j++){
      int n = t + 512*j;
      float xn = xrow[n];
      float xr = (n==0) ? 0.f : xrow[NN - n];
      fj[j] = xn + xr;
      dj[j] = xn - xr;
    }
    // FFT(f) -> 0.5*S2e (register se[16])
    fwd_s1_real(buf, aS1, fj, w1);
    __syncthreads();
    #pragma clang loop unroll(disable)
    for(int h=0; h<2; ++h) fwd_stage8<544,false>(buf, aS1 + 4352*h, wA);
    __syncthreads();
    #pragma clang loop unroll(disable)
    for(int h=0; h<2; ++h) fwd_stage8<68,false>(buf, aB + 4352*h, wB);
    __syncthreads();
    #pragma clang loop unroll(disable)
    for(int h=0; h<2; ++h) fwd_stage8<8,true>(buf, aC + 4352*h, wC);
    __syncthreads();
    #pragma clang loop unroll(disable)
    for(int h=0; h<2; ++h) fwd_stage_last8(buf, aM8 + 4352*h);
    __syncthreads();
    float se[16];
    #pragma unroll
    for(int j=0;j<8;j++){ se[j] = 0.5f * buf[aM8 + j].x; se[8+j] = 0.5f * buf[aM8 + 4352 + j].x; }
    __syncthreads();
    // FFT(d*phi) -> 0.5*S2o -> brow
    {
      float2 ph = make_float2(pcv, psv);
      float2 tmp[16];
      #pragma unroll
      for(int j=0;j<16;j++){ tmp[j] = make_float2(dj[j]*ph.x, dj[j]*ph.y); ph = cmul(ph, phstep); }
      fwd_s1_cplx(buf, aS1, tmp, w1);
    }
    __syncthreads();
    #pragma clang loop unroll(disable)
    for(int h=0; h<2; ++h) fwd_stage8<544,false>(buf, aS1 + 4352*h, wA);
    __syncthreads();
    #pragma clang loop unroll(disable)
    for(int h=0; h<2; ++h) fwd_stage8<68,false>(buf, aB + 4352*h, wB);
    __syncthreads();
    #pragma clang loop unroll(disable)
    for(int h=0; h<2; ++h) fwd_stage8<8,true>(buf, aC + 4352*h, wC);
    __syncthreads();
    #pragma clang loop unroll(disable)
    for(int h=0; h<2; ++h) fwd_stage_last8(buf, aM8 + 4352*h);
    __syncthreads();
    #pragma unroll
    for(int j=0;j<8;j++){
      brow[8*t + j]        = 0.5f * buf[aM8 + j].x;
      brow[4096 + 8*t + j] = 0.5f * buf[aM8 + 4352 + j].x;
    }
    __syncthreads();
    // FFT(c) -> Fc; G = Fc*(1 + i*se) -> gx (xrow) / gc (crow)
    #pragma unroll
    for(int j=0;j<16;j++) fj[j] = crow[t+512*j];
    fwd_s1_real(buf, aS1, fj, w1);
    __syncthreads();
    #pragma clang loop unroll(disable)
    for(int h=0; h<2; ++h) fwd_stage8<544,false>(buf, aS1 + 4352*h, wA);
    __syncthreads();
    #pragma clang loop unroll(disable)
    for(int h=0; h<2; ++h) fwd_stage8<68,false>(buf, aB + 4352*h, wB);
    __syncthreads();
    #pragma clang loop unroll(disable)
    for(int h=0; h<2; ++h) fwd_stage8<8,true>(buf, aC + 4352*h, wC);
    __syncthreads();
    #pragma clang loop unroll(disable)
    for(int h=0; h<2; ++h) fwd_stage_last8(buf, aM8 + 4352*h);
    __syncthreads();
    {
      float2* gx = (float2*)xrow;
      float2* gc = (float2*)crow;
      #pragma unroll
      for(int j=0;j<8;j++){
        float2 f0 = buf[aM8 + j];
        float2 f1 = buf[aM8 + 4352 + j];
        gx[8*t + j] = make_float2(fmaf(-f0.y, se[j],   f0.x), fmaf(f0.x, se[j],   f0.y));
        gc[8*t + j] = make_float2(fmaf(-f1.y, se[8+j], f1.x), fmaf(f1.x, se[8+j], f1.y));
      }
    }
    __syncthreads();
  }

  const float4* gp0 = (const float4*)((const float2*)xrow + 8*t);
  const float4* gp1 = (const float4*)((const float2*)crow + 8*t);
  const float4* sp0 = (const float4*)(brow + 8*t);
  const float4* sp1 = (const float4*)(brow + 4096 + 8*t);

  // --- 100 power iterations (rolled) ----------------------------------------
  #pragma clang loop unroll(disable)
  for(int iter=0; iter<100; ++iter){
    // Opaque redefinition: kills LICM hoisting/spilling of all twiddle chains.
    asm volatile("" : "+v"(c1v), "+v"(s1v), "+v"(cAv), "+v"(sAv),
                      "+v"(cBv), "+v"(sBv), "+v"(cCv), "+v"(sCv),
                      "+v"(pcv), "+v"(psv));
    const float2 w1 = make_float2(c1v,s1v), wA = make_float2(cAv,sAv),
                 wB = make_float2(cBv,sBv), wC = make_float2(cCv,sCv);
    float tot = iterate<false>(buf, red, t, breg, aS1, aB, aC, aM8,
                               w1, wA, wB, wC, pcv, psv, gp0, gp1, sp0, sp1);
    float s = rsqrtf(tot);
    #pragma unroll
    for(int j=0;j<16;j++) breg[j] *= s;
  }

  // --- final matvec for sigma ------------------------------------------------
  {
    asm volatile("" : "+v"(c1v), "+v"(s1v), "+v"(cAv), "+v"(sAv),
                      "+v"(cBv), "+v"(sBv), "+v"(cCv), "+v"(sCv),
                      "+v"(pcv), "+v"(psv));
    const float2 w1 = make_float2(c1v,s1v), wA = make_float2(cAv,sAv),
                 wB = make_float2(cBv,sBv), wC = make_float2(cCv,sCv);
    float tot = iterate<true>(buf, red, t, breg, aS1, aB, aC, aM8,
                              w1, wA, wB, wC, pcv, psv, gp0, gp1, sp0, sp1);
    if(t == 0) atomicAdd(out, fabsf(tot) * (1.f/512.f));
  }
}

extern "C" void kernel_launch(void* const* d_in, const int* in_sizes, int n_in,
                              void* d_out, int out_size, void* d_ws, size_t ws_size,
                              hipStream_t stream) {
  float* x    = (float*)d_in[0];
  float* circ = (float*)d_in[1];
  float* b0   = (float*)d_in[2];
  float* out  = (float*)d_out;

  hipLaunchKernelGGL(msvl_zero, dim3(1), dim3(1), 0, stream, out);
  hipLaunchKernelGGL(msvl_main, dim3(ROWS), dim3(NT), 0, stream,
                     x, circ, b0, out);
}

// Round 8
// 3802.097 us; speedup vs baseline: 4.6839x; 1.1655x over previous
//
#include <hip/hip_runtime.h>
#include <math.h>

// 512 rows of length 8192. Power iteration b <- normalize(b - T(x)C(c)b), 100x,
// then sigma = b.(b - TCb); out = mean(|sigma|).
//
// ROUND 18 KEY CHANGE: evict iteration-persistent state from VGPRs into LDS.
// Spill-traffic ledger (confirmed r16->r17: each live-state cut halves the
// phantom HBM traffic; r17 = 4.43 ms, WRITE 4.8 GB, FETCH 5.0 GB, VGPR still
// pinned at 128): remaining spill ~46 dwords/thread/iter == the persistent
// set: breg[16] (live across 12 phases that never use it) + 10 asm-pinned
// twiddle scalars (the "+v" hack FORCED them into VGPRs) + 4x 64-bit
// spectrum pointers. The allocator spills exactly these cold long-lived
// values around each phase.
// Fix:
//   - breg[16] -> bL[16*512] floats in LDS (per-thread column t; bank t%32,
//     2 lanes/bank = free). Read in fwd_s1_real, RMW in s1_junction/s1_final/
//     normalize. Same-thread only -> no barriers.
//   - 10 twiddle scalars -> tL[10*512] in LDS, written once, loaded per phase.
//     asm "+v" pin deleted; iteration-top asm volatile memory clobber stops
//     cross-iteration hoisting at zero register cost.
//   - Spectrum pointers rebuilt per call from uniform bases + per-thread
//     index (never persistent).
// Phase-local peak ~70 regs, persistent ~15 -> comfortably < 128.
// LDS: 69,632(buf) + 32(red) + 32,768(bL) + 20,480(tL) = 122,912 B.
//
// Radix-8 DIF math (verified r16/r17, absmax 0):
//   dft8: a[k]=y[k]+y[k+4]; b[k]=(y[k]-y[k+4])*W8^{Dk},
//         W8^{D}={1,(C2,D*C2),(0,D),(-C2,D*C2)}; dft4(a)->even, dft4(b)->odd.
//   Bin j lands at y[SIG[j]], SIG={0,4,1,5,2,6,3,7}; both directions store
//   slot j <- y[SIG[j]].
//   Twiddles: wA = e^{-2pi i t/4096}, wB = e^{-2pi i (t&63)/512},
//             wC = e^{-2pi i (t&7)/64}.
//
// LDS padding a(e) = e + (e>>4); padded affine offsets (carry-checked):
//   S1:      a = t+(t>>4) + 544q, mirror +4352
//   stage A: a = aS1 + 544k
//   stage B: a = (t>>6)*544 + (t&63)+((t&63)>>4) + 68k
//   stage C: a = (t>>3)*68 + (t&7) + 8k + (k>>1)
//   mid:     a = 8t + (t>>1) + k
//   half1 of any stage: +4352 (= pad(e+4096)-pad(e)).

#define NN 8192
#define NT 512
#define ROWS 512
#define BUFSZ 8704   // 8192 + 512 pad (float2)

__device__ __forceinline__ float2 cadd(float2 a, float2 b){ return make_float2(a.x+b.x, a.y+b.y); }
__device__ __forceinline__ float2 csub(float2 a, float2 b){ return make_float2(a.x-b.x, a.y-b.y); }
__device__ __forceinline__ float2 cmul(float2 a, float2 b){
  return make_float2(fmaf(a.x, b.x, -(a.y*b.y)), fmaf(a.x, b.y, a.y*b.x));
}
__device__ __forceinline__ float2 cscale(float2 a, float s){ return make_float2(a.x*s, a.y*s); }
__device__ __forceinline__ float2 conjf2(float2 a){ return make_float2(a.x, -a.y); }

static constexpr int SIG[8] = {0,4,1,5,2,6,3,7};   // bin j lives at y[SIG[j]]

template<int DIR> // DIR = -1 forward, +1 inverse
__device__ __forceinline__ void dft4(float2& a, float2& b, float2& c, float2& d){
  float2 t0=cadd(a,c), t1=csub(a,c), t2=cadd(b,d), t3=csub(b,d);
  float2 it3 = make_float2((float)(-DIR)*t3.y, (float)DIR*t3.x);
  a = cadd(t0,t2);
  c = csub(t0,t2);
  b = cadd(t1,it3);
  d = csub(t1,it3);
}

template<int DIR>
__device__ __forceinline__ void dft8i(float2 y[8]){
  const float C2 = 0.70710678119f;
  const float D  = (float)DIR;
  float2 a0=cadd(y[0],y[4]), a1=cadd(y[1],y[5]), a2=cadd(y[2],y[6]), a3=cadd(y[3],y[7]);
  float2 b0=csub(y[0],y[4]), b1=csub(y[1],y[5]), b2=csub(y[2],y[6]), b3=csub(y[3],y[7]);
  b1 = cmul(b1, make_float2(C2, D*C2));
  b2 = make_float2(-D*b2.y, D*b2.x);              // * (0, D)
  b3 = cmul(b3, make_float2(-C2, D*C2));
  dft4<DIR>(a0,a1,a2,a3);                          // even bins (natural)
  dft4<DIR>(b0,b1,b2,b3);                          // odd bins (natural)
  y[0]=a0; y[1]=a1; y[2]=a2; y[3]=a3;
  y[4]=b0; y[5]=b1; y[6]=b2; y[7]=b3;
}

// Padded offset within a stage: STEP*k (+ k>>1 for the st=8 stage).
template<int STEP, bool HK>
__device__ __forceinline__ constexpr int off8(int k){ return STEP*k + (HK ? (k>>1) : 0); }

// Forward radix-8 stage butterfly at padded base a0, per-thread twiddle w.
template<int STEP, bool HK>
__device__ __forceinline__ void fwd_stage8(float2* buf, int a0, float2 w){
  float2 y[8];
  #pragma unroll
  for(int k=0;k<8;k++) y[k] = buf[a0 + off8<STEP,HK>(k)];
  dft8i<-1>(y);
  float2 tw = make_float2(1.f,0.f);
  #pragma unroll
  for(int j=0;j<8;j++){
    buf[a0 + off8<STEP,HK>(j)] = cmul(y[SIG[j]], tw);
    tw = cmul(tw, w);
  }
}

// Inverse radix-8 stage (adjoint): load bin j from slot j * conj-tw^j,
// inverse network, store slot j <- y[SIG[j]] (time).
template<int STEP, bool HK>
__device__ __forceinline__ void inv_stage8(float2* buf, int a0, float2 w){
  float2 y[8];
  float2 tw = make_float2(1.f,0.f);
  #pragma unroll
  for(int k=0;k<8;k++){
    y[k] = cmul(buf[a0 + off8<STEP,HK>(k)], tw);
    tw = cmul(tw, w);
  }
  dft8i<1>(y);
  #pragma unroll
  for(int j=0;j<8;j++) buf[a0 + off8<STEP,HK>(j)] = y[SIG[j]];
}

// Last forward stage (precompute only): slot j <- bin j.
__device__ __forceinline__ void fwd_stage_last8(float2* buf, int aM){
  float2 y[8];
  #pragma unroll
  for(int k=0;k<8;k++) y[k] = buf[aM + k];
  dft8i<-1>(y);
  #pragma unroll
  for(int j=0;j<8;j++) buf[aM + j] = y[SIG[j]];
}

// Fused: fwd-last + complex-spectrum multiply (G, 4 float4 = 8 complex) + inv-first.
__device__ __forceinline__ void mid_junction_g8(float2* buf, int aM, const float4* gp){
  float2 y[8];
  #pragma unroll
  for(int k=0;k<8;k++) y[k] = buf[aM + k];
  dft8i<-1>(y);
  float2 z[8];
  #pragma unroll
  for(int j2=0;j2<4;j2++){
    float4 g = gp[j2];
    z[2*j2]   = cmul(y[SIG[2*j2]],   make_float2(g.x, g.y));
    z[2*j2+1] = cmul(y[SIG[2*j2+1]], make_float2(g.z, g.w));
  }
  dft8i<1>(z);
  #pragma unroll
  for(int k=0;k<8;k++) buf[aM + k] = z[SIG[k]];
}

// Fused: fwd-last + real-spectrum multiply (2 float4 = 8 reals) + inv-first.
__device__ __forceinline__ void mid_junction_s8(float2* buf, int aM, const float4* sp){
  float2 y[8];
  #pragma unroll
  for(int k=0;k<8;k++) y[k] = buf[aM + k];
  dft8i<-1>(y);
  float2 z[8];
  float4 s0 = sp[0], s1 = sp[1];
  z[0] = cscale(y[SIG[0]], s0.x);
  z[1] = cscale(y[SIG[1]], s0.y);
  z[2] = cscale(y[SIG[2]], s0.z);
  z[3] = cscale(y[SIG[3]], s0.w);
  z[4] = cscale(y[SIG[4]], s1.x);
  z[5] = cscale(y[SIG[5]], s1.y);
  z[6] = cscale(y[SIG[6]], s1.z);
  z[7] = cscale(y[SIG[7]], s1.w);
  dft8i<1>(z);
  #pragma unroll
  for(int k=0;k<8;k++) buf[aM + k] = z[SIG[k]];
}

// ---- S1 (radix-2) + epilogues; breg lives in LDS column bL[j*512+t] --------

// S1 fwd reading b from LDS (in-loop).
__device__ __forceinline__ void fwd_s1_real_l(float2* buf, const float* bL, int t,
                                              int aS1, float2 w1){
  float2 tw = w1;
  const float2 step = make_float2(0.92387953251f, -0.38268343236f); // e^{-i pi/8}
  #pragma unroll
  for(int q=0;q<8;q++){
    int a = aS1 + 544*q;
    float bq  = bL[q*512 + t];
    float bq8 = bL[(q+8)*512 + t];
    float d = bq - bq8;
    buf[a]        = make_float2(bq + bq8, 0.f);
    buf[a + 4352] = make_float2(d*tw.x, d*tw.y);
    tw = cmul(tw, step);
  }
}

// S1 fwd from real regs (precompute only).
__device__ __forceinline__ void fwd_s1_real(float2* buf, int aS1, const float b[16], float2 w1){
  float2 tw = w1;
  const float2 step = make_float2(0.92387953251f, -0.38268343236f);
  #pragma unroll
  for(int q=0;q<8;q++){
    int a = aS1 + 544*q;
    float d = b[q] - b[q+8];
    buf[a]        = make_float2(b[q] + b[q+8], 0.f);
    buf[a + 4352] = make_float2(d*tw.x, d*tw.y);
    tw = cmul(tw, step);
  }
}

// S1 fwd from complex regs (precompute only).
__device__ __forceinline__ void fwd_s1_cplx(float2* buf, int aS1, const float2 in[16], float2 w1){
  float2 tw = w1;
  const float2 step = make_float2(0.92387953251f, -0.38268343236f);
  #pragma unroll
  for(int q=0;q<8;q++){
    int a = aS1 + 544*q;
    buf[a]        = cadd(in[q], in[q+8]);
    buf[a + 4352] = cmul(csub(in[q], in[q+8]), tw);
    tw = cmul(tw, step);
  }
}

// Fused: inv-S1 + epilogue1 + phi-modulate + fwd-S1. breg RMW in LDS.
template<bool SIGMA>
__device__ __forceinline__ void s1_junction_l(float2* buf, float* bL, int t, int aS1,
                                              float& loc, float2 w1, float pc, float ps,
                                              float sc1){
  float2 twi = conjf2(w1), twf = w1;
  const float2 stepi = make_float2(0.92387953251f,  0.38268343236f);
  const float2 stepf = make_float2(0.92387953251f, -0.38268343236f);
  float2 ph = make_float2(pc, ps);
  const float2 phstep = make_float2(0.98078528040f, -0.19509032202f); // e^{-i pi/16}
  #pragma unroll
  for(int q=0;q<8;q++){
    int a = aS1 + 544*q;
    float2 z0 = buf[a];
    float2 z1 = cmul(buf[a + 4352], twi);
    float2 zn = cscale(cadd(z0,z1), sc1);
    float2 zm = cscale(csub(z0,z1), sc1);
    if (SIGMA) {
      float bq  = bL[q*512 + t];
      float bq8 = bL[(q+8)*512 + t];
      loc += bq*(bq-zn.y) + bq8*(bq8-zm.y);
    } else {
      bL[q*512 + t]     -= zn.y;
      bL[(q+8)*512 + t] -= zm.y;
    }
    float2 vn = make_float2(zn.x*ph.x,  zn.x*ph.y);
    float2 vm = make_float2(zm.x*ph.y, -zm.x*ph.x);
    buf[a]        = cadd(vn, vm);
    buf[a + 4352] = cmul(csub(vn, vm), twf);
    twi = cmul(twi, stepi); twf = cmul(twf, stepf); ph = cmul(ph, phstep);
  }
}

// Fused: inv-S1 + epilogue2. breg RMW in LDS.
template<bool SIGMA>
__device__ __forceinline__ void s1_final_l(float2* buf, float* bL, int t, int aS1,
                                           float& loc, float2 w1, float pc, float ps,
                                           float sc2){
  float2 twi = conjf2(w1);
  const float2 stepi = make_float2(0.92387953251f, 0.38268343236f);
  float2 ph = make_float2(pc, ps);
  const float2 phstep = make_float2(0.98078528040f, -0.19509032202f);
  #pragma unroll
  for(int q=0;q<8;q++){
    int a = aS1 + 544*q;
    float2 z0 = buf[a];
    float2 z1 = cmul(buf[a + 4352], twi);
    float2 yn = cscale(cadd(z0,z1), sc2);
    float2 ym = cscale(csub(z0,z1), sc2);
    float qn = fmaf(ph.x, yn.x,  ph.y*yn.y);
    float qm = fmaf(ph.y, ym.x, -ph.x*ym.y);
    if (SIGMA) {
      float bq  = bL[q*512 + t];
      float bq8 = bL[(q+8)*512 + t];
      loc -= bq*qn + bq8*qm;
    } else {
      float bn = bL[q*512 + t] - qn;
      bL[q*512 + t] = bn; loc = fmaf(bn,bn,loc);
      bn = bL[(q+8)*512 + t] - qm;
      bL[(q+8)*512 + t] = bn; loc = fmaf(bn,bn,loc);
    }
    twi = cmul(twi, stepi); ph = cmul(ph, phstep);
  }
}

// One full iteration; all persistent state in LDS (bL breg, tL twiddles).
template<bool SIGMA>
__device__ __forceinline__ float iterate(float2* buf, float* red, float* bL, const float* tL,
                                         int t, int aS1, int aB, int aC, int aM8,
                                         const float4* gx4, const float4* gc4,
                                         const float4* sb4){
  const float sc1 = 1.f/8192.f, sc2 = 1.f/8192.f;
  float loc = 0.f;

  {
    float2 w1 = make_float2(tL[t], tL[512+t]);
    fwd_s1_real_l(buf, bL, t, aS1, w1);
  }
  __syncthreads();
  #pragma clang loop unroll(disable)
  for(int h=0; h<2; ++h){
    float2 wA = make_float2(tL[2*512+t], tL[3*512+t]);
    fwd_stage8<544,false>(buf, aS1 + 4352*h, wA);
  }
  __syncthreads();
  #pragma clang loop unroll(disable)
  for(int h=0; h<2; ++h){
    float2 wB = make_float2(tL[4*512+t], tL[5*512+t]);
    fwd_stage8<68,false>(buf, aB + 4352*h, wB);
  }
  __syncthreads();
  #pragma clang loop unroll(disable)
  for(int h=0; h<2; ++h){
    float2 wC = make_float2(tL[6*512+t], tL[7*512+t]);
    fwd_stage8<8,true>(buf, aC + 4352*h, wC);
  }
  __syncthreads();
  #pragma clang loop unroll(disable)
  for(int h=0; h<2; ++h){
    mid_junction_g8(buf, aM8 + 4352*h, (h ? gc4 : gx4) + 4*t);
  }
  __syncthreads();
  #pragma clang loop unroll(disable)
  for(int h=0; h<2; ++h){
    float2 wCc = make_float2(tL[6*512+t], -tL[7*512+t]);
    inv_stage8<8,true>(buf, aC + 4352*h, wCc);
  }
  __syncthreads();
  #pragma clang loop unroll(disable)
  for(int h=0; h<2; ++h){
    float2 wBc = make_float2(tL[4*512+t], -tL[5*512+t]);
    inv_stage8<68,false>(buf, aB + 4352*h, wBc);
  }
  __syncthreads();
  #pragma clang loop unroll(disable)
  for(int h=0; h<2; ++h){
    float2 wAc = make_float2(tL[2*512+t], -tL[3*512+t]);
    inv_stage8<544,false>(buf, aS1 + 4352*h, wAc);
  }
  __syncthreads();
  {
    float2 w1 = make_float2(tL[t], tL[512+t]);
    s1_junction_l<SIGMA>(buf, bL, t, aS1, loc, w1, tL[8*512+t], tL[9*512+t], sc1);
  }
  __syncthreads();
  #pragma clang loop unroll(disable)
  for(int h=0; h<2; ++h){
    float2 wA = make_float2(tL[2*512+t], tL[3*512+t]);
    fwd_stage8<544,false>(buf, aS1 + 4352*h, wA);
  }
  __syncthreads();
  #pragma clang loop unroll(disable)
  for(int h=0; h<2; ++h){
    float2 wB = make_float2(tL[4*512+t], tL[5*512+t]);
    fwd_stage8<68,false>(buf, aB + 4352*h, wB);
  }
  __syncthreads();
  #pragma clang loop unroll(disable)
  for(int h=0; h<2; ++h){
    float2 wC = make_float2(tL[6*512+t], tL[7*512+t]);
    fwd_stage8<8,true>(buf, aC + 4352*h, wC);
  }
  __syncthreads();
  #pragma clang loop unroll(disable)
  for(int h=0; h<2; ++h){
    mid_junction_s8(buf, aM8 + 4352*h, sb4 + (h ? 1024 + 2*t : 2*t));
  }
  __syncthreads();
  #pragma clang loop unroll(disable)
  for(int h=0; h<2; ++h){
    float2 wCc = make_float2(tL[6*512+t], -tL[7*512+t]);
    inv_stage8<8,true>(buf, aC + 4352*h, wCc);
  }
  __syncthreads();
  #pragma clang loop unroll(disable)
  for(int h=0; h<2; ++h){
    float2 wBc = make_float2(tL[4*512+t], -tL[5*512+t]);
    inv_stage8<68,false>(buf, aB + 4352*h, wBc);
  }
  __syncthreads();
  #pragma clang loop unroll(disable)
  for(int h=0; h<2; ++h){
    float2 wAc = make_float2(tL[2*512+t], -tL[3*512+t]);
    inv_stage8<544,false>(buf, aS1 + 4352*h, wAc);
  }
  __syncthreads();
  {
    float2 w1 = make_float2(tL[t], tL[512+t]);
    s1_final_l<SIGMA>(buf, bL, t, aS1, loc, w1, tL[8*512+t], tL[9*512+t], sc2);
  }

  __syncthreads();
  #pragma unroll
  for(int off=32; off; off>>=1) loc += __shfl_down(loc, off, 64);
  if((t&63)==0) red[t>>6] = loc;
  __syncthreads();
  float tot = 0.f;
  #pragma unroll
  for(int w=0;w<8;w++) tot += red[w];
  __syncthreads();
  return tot;
}

__global__ void msvl_zero(float* out){ out[0] = 0.f; }

__global__ void __launch_bounds__(512)
msvl_main(float* x, float* circ, float* b0, float* out){
  __shared__ float2 buf[BUFSZ];        // 69,632 B
  __shared__ float red[8];
  __shared__ float bL[16*512];         // 32,768 B  breg columns
  __shared__ float tL[10*512];         // 20,480 B  twiddle stash
  const int t = threadIdx.x;
  const int row = blockIdx.x;

  float* xrow = x    + (size_t)row * NN;
  float* crow = circ + (size_t)row * NN;
  float* brow = b0   + (size_t)row * NN;

  // Padded per-thread bases (iteration-invariant).
  const int aS1 = t + (t>>4);                              // also stage-A base
  const int aB  = (t>>6)*544 + (t&63) + ((t&63)>>4);       // stage B
  const int aC  = (t>>3)*68 + (t&7);                       // stage C
  const int aM8 = 8*t + (t>>1);                            // mid blocks

  // Twiddle scalars: computed once, stashed to LDS (regs freed after precompute).
  float s1v,c1v,sAv,cAv,sBv,cBv,sCv,cCv,psv,pcv;
  __sincosf(-6.28318530718f*(float)t/8192.f,       &s1v,&c1v);   // w1 (S1)
  __sincosf(-6.28318530718f*(float)t/4096.f,       &sAv,&cAv);   // wA (st=512)
  __sincosf(-6.28318530718f*(float)(t&63)/512.f,   &sBv,&cBv);   // wB (st=64)
  __sincosf(-6.28318530718f*(float)(t&7)/64.f,     &sCv,&cCv);   // wC (st=8)
  __sincosf(-3.14159265359f*(float)t/8192.f,       &psv,&pcv);   // phi
  const float2 phstep = make_float2(0.98078528040f, -0.19509032202f);
  tL[0*512+t]=c1v; tL[1*512+t]=s1v;
  tL[2*512+t]=cAv; tL[3*512+t]=sAv;
  tL[4*512+t]=cBv; tL[5*512+t]=sBv;
  tL[6*512+t]=cCv; tL[7*512+t]=sCv;
  tL[8*512+t]=pcv; tL[9*512+t]=psv;

  // --- init: b = b0 / ||b0|| -> bL  (precedes spectra overwrite of brow) ----
  {
    float nrm = 0.f;
    #pragma unroll
    for(int j=0;j<16;j++){ float v = brow[t+512*j]; bL[j*512+t]=v; nrm = fmaf(v,v,nrm); }
    #pragma unroll
    for(int off=32; off; off>>=1) nrm += __shfl_down(nrm, off, 64);
    if((t&63)==0) red[t>>6] = nrm;
    __syncthreads();
    float tot = 0.f;
    #pragma unroll
    for(int w=0;w<8;w++) tot += red[w];
    float isc = rsqrtf(tot);
    #pragma unroll
    for(int j=0;j<16;j++) bL[j*512+t] *= isc;
  }

  // --- precompute spectra (3 forward FFTs) -> global ------------------------
  // G: gx[8t+j] (xrow), gc[8t+j] (crow);  S2o: brow[8t+j], brow[4096+8t+j].
  {
    const float2 w1 = make_float2(c1v,s1v), wA = make_float2(cAv,sAv),
                 wB = make_float2(cBv,sBv), wC = make_float2(cCv,sCv);
    float fj[16], dj[16];
    #pragma unroll
    for(int j=0;j<16;j++){
      int n = t + 512*j;
      float xn = xrow[n];
      float xr = (n==0) ? 0.f : xrow[NN - n];
      fj[j] = xn + xr;
      dj[j] = xn - xr;
    }
    // FFT(f) -> 0.5*S2e (register se[16])
    fwd_s1_real(buf, aS1, fj, w1);
    __syncthreads();
    #pragma clang loop unroll(disable)
    for(int h=0; h<2; ++h) fwd_stage8<544,false>(buf, aS1 + 4352*h, wA);
    __syncthreads();
    #pragma clang loop unroll(disable)
    for(int h=0; h<2; ++h) fwd_stage8<68,false>(buf, aB + 4352*h, wB);
    __syncthreads();
    #pragma clang loop unroll(disable)
    for(int h=0; h<2; ++h) fwd_stage8<8,true>(buf, aC + 4352*h, wC);
    __syncthreads();
    #pragma clang loop unroll(disable)
    for(int h=0; h<2; ++h) fwd_stage_last8(buf, aM8 + 4352*h);
    __syncthreads();
    float se[16];
    #pragma unroll
    for(int j=0;j<8;j++){ se[j] = 0.5f * buf[aM8 + j].x; se[8+j] = 0.5f * buf[aM8 + 4352 + j].x; }
    __syncthreads();
    // FFT(d*phi) -> 0.5*S2o -> brow
    {
      float2 ph = make_float2(pcv, psv);
      float2 tmp[16];
      #pragma unroll
      for(int j=0;j<16;j++){ tmp[j] = make_float2(dj[j]*ph.x, dj[j]*ph.y); ph = cmul(ph, phstep); }
      fwd_s1_cplx(buf, aS1, tmp, w1);
    }
    __syncthreads();
    #pragma clang loop unroll(disable)
    for(int h=0; h<2; ++h) fwd_stage8<544,false>(buf, aS1 + 4352*h, wA);
    __syncthreads();
    #pragma clang loop unroll(disable)
    for(int h=0; h<2; ++h) fwd_stage8<68,false>(buf, aB + 4352*h, wB);
    __syncthreads();
    #pragma clang loop unroll(disable)
    for(int h=0; h<2; ++h) fwd_stage8<8,true>(buf, aC + 4352*h, wC);
    __syncthreads();
    #pragma clang loop unroll(disable)
    for(int h=0; h<2; ++h) fwd_stage_last8(buf, aM8 + 4352*h);
    __syncthreads();
    #pragma unroll
    for(int j=0;j<8;j++){
      brow[8*t + j]        = 0.5f * buf[aM8 + j].x;
      brow[4096 + 8*t + j] = 0.5f * buf[aM8 + 4352 + j].x;
    }
    __syncthreads();
    // FFT(c) -> Fc; G = Fc*(1 + i*se) -> gx (xrow) / gc (crow)
    #pragma unroll
    for(int j=0;j<16;j++) fj[j] = crow[t+512*j];
    fwd_s1_real(buf, aS1, fj, w1);
    __syncthreads();
    #pragma clang loop unroll(disable)
    for(int h=0; h<2; ++h) fwd_stage8<544,false>(buf, aS1 + 4352*h, wA);
    __syncthreads();
    #pragma clang loop unroll(disable)
    for(int h=0; h<2; ++h) fwd_stage8<68,false>(buf, aB + 4352*h, wB);
    __syncthreads();
    #pragma clang loop unroll(disable)
    for(int h=0; h<2; ++h) fwd_stage8<8,true>(buf, aC + 4352*h, wC);
    __syncthreads();
    #pragma clang loop unroll(disable)
    for(int h=0; h<2; ++h) fwd_stage_last8(buf, aM8 + 4352*h);
    __syncthreads();
    {
      float2* gx = (float2*)xrow;
      float2* gc = (float2*)crow;
      #pragma unroll
      for(int j=0;j<8;j++){
        float2 f0 = buf[aM8 + j];
        float2 f1 = buf[aM8 + 4352 + j];
        gx[8*t + j] = make_float2(fmaf(-f0.y, se[j],   f0.x), fmaf(f0.x, se[j],   f0.y));
        gc[8*t + j] = make_float2(fmaf(-f1.y, se[8+j], f1.x), fmaf(f1.x, se[8+j], f1.y));
      }
    }
    __syncthreads();
  }

  const float4* gx4 = (const float4*)xrow;
  const float4* gc4 = (const float4*)crow;
  const float4* sb4 = (const float4*)brow;

  // --- 100 power iterations (rolled) ----------------------------------------
  #pragma clang loop unroll(disable)
  for(int iter=0; iter<100; ++iter){
    asm volatile("" ::: "memory");   // no cross-iteration hoisting of LDS state
    float tot = iterate<false>(buf, red, bL, tL, t, aS1, aB, aC, aM8,
                               gx4, gc4, sb4);
    float s = rsqrtf(tot);
    #pragma unroll
    for(int j=0;j<16;j++) bL[j*512+t] *= s;
  }

  // --- final matvec for sigma ------------------------------------------------
  {
    asm volatile("" ::: "memory");
    float tot = iterate<true>(buf, red, bL, tL, t, aS1, aB, aC, aM8,
                              gx4, gc4, sb4);
    if(t == 0) atomicAdd(out, fabsf(tot) * (1.f/512.f));
  }
}

extern "C" void kernel_launch(void* const* d_in, const int* in_sizes, int n_in,
                              void* d_out, int out_size, void* d_ws, size_t ws_size,
                              hipStream_t stream) {
  float* x    = (float*)d_in[0];
  float* circ = (float*)d_in[1];
  float* b0   = (float*)d_in[2];
  float* out  = (float*)d_out;

  hipLaunchKernelGGL(msvl_zero, dim3(1), dim3(1), 0, stream, out);
  hipLaunchKernelGGL(msvl_main, dim3(ROWS), dim3(NT), 0, stream,
                     x, circ, b0, out);
}

// Round 9
// 3178.695 us; speedup vs baseline: 5.6025x; 1.1961x over previous
//
#include <hip/hip_runtime.h>
#include <math.h>

// 512 rows of length 8192. Power iteration b <- normalize(b - T(x)C(c)b), 100x,
// then sigma = b.(b - TCb); out = mean(|sigma|).
//
// ROUND 19 KEY CHANGE: barrier-topology optimization. r18 closed the spill
// saga (VGPR 112, WRITE 49 MB, HBM ~0) -> kernel is now on-chip bound:
// VALUBusy 60%, 16 block barriers/iter serializing 8 waves into lockstep.
// Data-flow analysis of the 4-stage radix-8 FFT (8192 = 2 x 8^4):
//   - S1 <-> stage-A exchange is SAME-THREAD (element t+512k both sides):
//     fuse S1+A in registers, skip the LDS round-trip and its barriers.
//       P1 = S1-fwd + A-fwd;  P3 = A-inv + epilogue1 + S1-fwd + A-fwd;
//       P5 = A-inv + epilogue2.   (bitwise-identical arithmetic, same order)
//   - B -> C -> mid -> C-inv -> B-inv exchanges are INTRA-WAVE: stage-B's
//     512-elem group = threads 64g..64g+63 = exactly one wave; C's 64-groups
//     and mid's 8-blocks nest inside. Same-wave LDS ops execute in order in
//     the LDS pipe -> replace these 8 barriers with compile-time fences
//     (asm memory clobber + __builtin_amdgcn_sched_barrier(0): no runtime
//     cost, just forbids compiler/backend reordering of ds ops).
//   - Only A->B and B-inv->A-inv are cross-wave (A spans all 8 waves):
//     4 real barriers + 2 reduction barriers per iter, was 16.
// Also removes ~96 LDS ops/thread/iter (the S1/A round-trips).
//
// Radix-8 DIF math (verified r16-r18, absmax 0):
//   dft8: a[k]=y[k]+y[k+4]; b[k]=(y[k]-y[k+4])*W8^{Dk},
//         W8^{D}={1,(C2,D*C2),(0,D),(-C2,D*C2)}; dft4(a)->even, dft4(b)->odd.
//   Bin j lands at y[SIG[j]], SIG={0,4,1,5,2,6,3,7}; both directions store
//   slot j <- y[SIG[j]].
//   Twiddles: wA = e^{-2pi i t/4096}, wB = e^{-2pi i (t&63)/512},
//             wC = e^{-2pi i (t&7)/64}.
//
// LDS padding a(e) = e + (e>>4); padded affine offsets (carry-checked):
//   S1/A:    a = t+(t>>4) + 544k, mirror +4352
//   stage B: a = (t>>6)*544 + (t&63)+((t&63)>>4) + 68k
//   stage C: a = (t>>3)*68 + (t&7) + 8k + (k>>1)
//   mid:     a = 8t + (t>>1) + k
//   half1 of any stage: +4352 (= pad(e+4096)-pad(e)).
//
// Persistent state in LDS (r18): bL[16*512] breg columns, tL[10*512] twiddles.
// LDS total: 69,632(buf) + 32(red) + 32,768(bL) + 20,480(tL) = 122,912 B.

#define NN 8192
#define NT 512
#define ROWS 512
#define BUFSZ 8704   // 8192 + 512 pad (float2)

__device__ __forceinline__ float2 cadd(float2 a, float2 b){ return make_float2(a.x+b.x, a.y+b.y); }
__device__ __forceinline__ float2 csub(float2 a, float2 b){ return make_float2(a.x-b.x, a.y-b.y); }
__device__ __forceinline__ float2 cmul(float2 a, float2 b){
  return make_float2(fmaf(a.x, b.x, -(a.y*b.y)), fmaf(a.x, b.y, a.y*b.x));
}
__device__ __forceinline__ float2 cscale(float2 a, float s){ return make_float2(a.x*s, a.y*s); }
__device__ __forceinline__ float2 conjf2(float2 a){ return make_float2(a.x, -a.y); }

// Wave-internal ordering fence: no runtime cost; forbids compiler/backend
// reordering of LDS ops across it. Cross-lane data inside one wave is safe
// because same-wave ds ops are processed in order by the LDS pipe.
__device__ __forceinline__ void wfence(){
  asm volatile("" ::: "memory");
  __builtin_amdgcn_sched_barrier(0);
}

static constexpr int SIG[8] = {0,4,1,5,2,6,3,7};   // bin j lives at y[SIG[j]]

template<int DIR> // DIR = -1 forward, +1 inverse
__device__ __forceinline__ void dft4(float2& a, float2& b, float2& c, float2& d){
  float2 t0=cadd(a,c), t1=csub(a,c), t2=cadd(b,d), t3=csub(b,d);
  float2 it3 = make_float2((float)(-DIR)*t3.y, (float)DIR*t3.x);
  a = cadd(t0,t2);
  c = csub(t0,t2);
  b = cadd(t1,it3);
  d = csub(t1,it3);
}

template<int DIR>
__device__ __forceinline__ void dft8i(float2 y[8]){
  const float C2 = 0.70710678119f;
  const float D  = (float)DIR;
  float2 a0=cadd(y[0],y[4]), a1=cadd(y[1],y[5]), a2=cadd(y[2],y[6]), a3=cadd(y[3],y[7]);
  float2 b0=csub(y[0],y[4]), b1=csub(y[1],y[5]), b2=csub(y[2],y[6]), b3=csub(y[3],y[7]);
  b1 = cmul(b1, make_float2(C2, D*C2));
  b2 = make_float2(-D*b2.y, D*b2.x);              // * (0, D)
  b3 = cmul(b3, make_float2(-C2, D*C2));
  dft4<DIR>(a0,a1,a2,a3);                          // even bins (natural)
  dft4<DIR>(b0,b1,b2,b3);                          // odd bins (natural)
  y[0]=a0; y[1]=a1; y[2]=a2; y[3]=a3;
  y[4]=b0; y[5]=b1; y[6]=b2; y[7]=b3;
}

// Padded offset within a stage: STEP*k (+ k>>1 for the st=8 stage).
template<int STEP, bool HK>
__device__ __forceinline__ constexpr int off8(int k){ return STEP*k + (HK ? (k>>1) : 0); }

// Forward radix-8 stage butterfly at padded base a0, per-thread twiddle w.
template<int STEP, bool HK>
__device__ __forceinline__ void fwd_stage8(float2* buf, int a0, float2 w){
  float2 y[8];
  #pragma unroll
  for(int k=0;k<8;k++) y[k] = buf[a0 + off8<STEP,HK>(k)];
  dft8i<-1>(y);
  float2 tw = make_float2(1.f,0.f);
  #pragma unroll
  for(int j=0;j<8;j++){
    buf[a0 + off8<STEP,HK>(j)] = cmul(y[SIG[j]], tw);
    tw = cmul(tw, w);
  }
}

// Inverse radix-8 stage (adjoint).
template<int STEP, bool HK>
__device__ __forceinline__ void inv_stage8(float2* buf, int a0, float2 w){
  float2 y[8];
  float2 tw = make_float2(1.f,0.f);
  #pragma unroll
  for(int k=0;k<8;k++){
    y[k] = cmul(buf[a0 + off8<STEP,HK>(k)], tw);
    tw = cmul(tw, w);
  }
  dft8i<1>(y);
  #pragma unroll
  for(int j=0;j<8;j++) buf[a0 + off8<STEP,HK>(j)] = y[SIG[j]];
}

// Last forward stage (precompute only): slot j <- bin j.
__device__ __forceinline__ void fwd_stage_last8(float2* buf, int aM){
  float2 y[8];
  #pragma unroll
  for(int k=0;k<8;k++) y[k] = buf[aM + k];
  dft8i<-1>(y);
  #pragma unroll
  for(int j=0;j<8;j++) buf[aM + j] = y[SIG[j]];
}

// Fused: fwd-last + complex-spectrum multiply (G) + inv-first.
__device__ __forceinline__ void mid_junction_g8(float2* buf, int aM, const float4* gp){
  float2 y[8];
  #pragma unroll
  for(int k=0;k<8;k++) y[k] = buf[aM + k];
  dft8i<-1>(y);
  float2 z[8];
  #pragma unroll
  for(int j2=0;j2<4;j2++){
    float4 g = gp[j2];
    z[2*j2]   = cmul(y[SIG[2*j2]],   make_float2(g.x, g.y));
    z[2*j2+1] = cmul(y[SIG[2*j2+1]], make_float2(g.z, g.w));
  }
  dft8i<1>(z);
  #pragma unroll
  for(int k=0;k<8;k++) buf[aM + k] = z[SIG[k]];
}

// Fused: fwd-last + real-spectrum multiply + inv-first.
__device__ __forceinline__ void mid_junction_s8(float2* buf, int aM, const float4* sp){
  float2 y[8];
  #pragma unroll
  for(int k=0;k<8;k++) y[k] = buf[aM + k];
  dft8i<-1>(y);
  float2 z[8];
  float4 s0 = sp[0], s1 = sp[1];
  z[0] = cscale(y[SIG[0]], s0.x);
  z[1] = cscale(y[SIG[1]], s0.y);
  z[2] = cscale(y[SIG[2]], s0.z);
  z[3] = cscale(y[SIG[3]], s0.w);
  z[4] = cscale(y[SIG[4]], s1.x);
  z[5] = cscale(y[SIG[5]], s1.y);
  z[6] = cscale(y[SIG[6]], s1.z);
  z[7] = cscale(y[SIG[7]], s1.w);
  dft8i<1>(z);
  #pragma unroll
  for(int k=0;k<8;k++) buf[aM + k] = z[SIG[k]];
}

// ---- precompute-only S1 helpers (write LDS; barrier follows) ---------------

__device__ __forceinline__ void fwd_s1_real(float2* buf, int aS1, const float b[16], float2 w1){
  float2 tw = w1;
  const float2 step = make_float2(0.92387953251f, -0.38268343236f); // e^{-i pi/8}
  #pragma unroll
  for(int q=0;q<8;q++){
    int a = aS1 + 544*q;
    float d = b[q] - b[q+8];
    buf[a]        = make_float2(b[q] + b[q+8], 0.f);
    buf[a + 4352] = make_float2(d*tw.x, d*tw.y);
    tw = cmul(tw, step);
  }
}

__device__ __forceinline__ void fwd_s1_cplx(float2* buf, int aS1, const float2 in[16], float2 w1){
  float2 tw = w1;
  const float2 step = make_float2(0.92387953251f, -0.38268343236f);
  #pragma unroll
  for(int q=0;q<8;q++){
    int a = aS1 + 544*q;
    buf[a]        = cadd(in[q], in[q+8]);
    buf[a + 4352] = cmul(csub(in[q], in[q+8]), tw);
    tw = cmul(tw, step);
  }
}

// ---- in-loop fused phases (same-thread S1<->A, all in registers) -----------

// P1: S1-fwd (from bL) + stage-A-fwd, both halves. Writes buf t+512k slots.
__device__ __forceinline__ void p1_s1_a_fwd(float2* buf, const float* bL, const float* tL,
                                            int t, int aS1){
  float2 w1 = make_float2(tL[t], tL[512+t]);
  float2 wA = make_float2(tL[2*512+t], tL[3*512+t]);
  float2 n[8], m[8];
  {
    float2 tw = w1;
    const float2 step = make_float2(0.92387953251f, -0.38268343236f);
    #pragma unroll
    for(int q=0;q<8;q++){
      float bq = bL[q*512+t], bq8 = bL[(q+8)*512+t];
      float d = bq - bq8;
      n[q] = make_float2(bq + bq8, 0.f);
      m[q] = make_float2(d*tw.x, d*tw.y);
      tw = cmul(tw, step);
    }
  }
  dft8i<-1>(n);
  {
    float2 tw = make_float2(1.f,0.f);
    #pragma unroll
    for(int j=0;j<8;j++){ buf[aS1 + 544*j] = cmul(n[SIG[j]], tw); tw = cmul(tw, wA); }
  }
  dft8i<-1>(m);
  {
    float2 tw = make_float2(1.f,0.f);
    #pragma unroll
    for(int j=0;j<8;j++){ buf[aS1 + 4352 + 544*j] = cmul(m[SIG[j]], tw); tw = cmul(tw, wA); }
  }
}

// P3: A-inv + inv-S1 + epilogue1 + phi-modulate + S1-fwd + A-fwd.
template<bool SIGMA>
__device__ __forceinline__ void p3_ainv_junc_afwd(float2* buf, float* bL, const float* tL,
                                                  int t, int aS1, float& loc, float sc1){
  float2 w1 = make_float2(tL[t], tL[512+t]);
  float2 wA = make_float2(tL[2*512+t], tL[3*512+t]);
  float2 wAc = conjf2(wA);
  float2 y0[8], y1[8];
  { float2 tw = make_float2(1.f,0.f);
    #pragma unroll
    for(int k=0;k<8;k++){ y0[k] = cmul(buf[aS1 + 544*k], tw); tw = cmul(tw, wAc); } }
  dft8i<1>(y0);
  { float2 tw = make_float2(1.f,0.f);
    #pragma unroll
    for(int k=0;k<8;k++){ y1[k] = cmul(buf[aS1 + 4352 + 544*k], tw); tw = cmul(tw, wAc); } }
  dft8i<1>(y1);
  // time sample at slot q: half0 = y0[SIG[q]], half1 = y1[SIG[q]]
  float2 n[8], m[8];
  {
    float2 twi = conjf2(w1), twf = w1;
    const float2 stepi = make_float2(0.92387953251f,  0.38268343236f);
    const float2 stepf = make_float2(0.92387953251f, -0.38268343236f);
    float2 ph = make_float2(tL[8*512+t], tL[9*512+t]);
    const float2 phstep = make_float2(0.98078528040f, -0.19509032202f);
    #pragma unroll
    for(int q=0;q<8;q++){
      float2 z0 = y0[SIG[q]];
      float2 z1 = cmul(y1[SIG[q]], twi);
      float2 zn = cscale(cadd(z0,z1), sc1);
      float2 zm = cscale(csub(z0,z1), sc1);
      if (SIGMA) {
        float bq = bL[q*512+t], bq8 = bL[(q+8)*512+t];
        loc += bq*(bq-zn.y) + bq8*(bq8-zm.y);
      } else {
        bL[q*512+t]     -= zn.y;
        bL[(q+8)*512+t] -= zm.y;
      }
      float2 vn = make_float2(zn.x*ph.x,  zn.x*ph.y);
      float2 vm = make_float2(zm.x*ph.y, -zm.x*ph.x);
      n[q] = cadd(vn, vm);
      m[q] = cmul(csub(vn, vm), twf);
      twi = cmul(twi, stepi); twf = cmul(twf, stepf); ph = cmul(ph, phstep);
    }
  }
  dft8i<-1>(n);
  { float2 tw = make_float2(1.f,0.f);
    #pragma unroll
    for(int j=0;j<8;j++){ buf[aS1 + 544*j] = cmul(n[SIG[j]], tw); tw = cmul(tw, wA); } }
  dft8i<-1>(m);
  { float2 tw = make_float2(1.f,0.f);
    #pragma unroll
    for(int j=0;j<8;j++){ buf[aS1 + 4352 + 544*j] = cmul(m[SIG[j]], tw); tw = cmul(tw, wA); } }
}

// P5: A-inv + inv-S1 + epilogue2 (updates bL, loc).
template<bool SIGMA>
__device__ __forceinline__ void p5_ainv_final(float2* buf, float* bL, const float* tL,
                                              int t, int aS1, float& loc, float sc2){
  float2 w1 = make_float2(tL[t], tL[512+t]);
  float2 wAc = make_float2(tL[2*512+t], -tL[3*512+t]);
  float2 y0[8], y1[8];
  { float2 tw = make_float2(1.f,0.f);
    #pragma unroll
    for(int k=0;k<8;k++){ y0[k] = cmul(buf[aS1 + 544*k], tw); tw = cmul(tw, wAc); } }
  dft8i<1>(y0);
  { float2 tw = make_float2(1.f,0.f);
    #pragma unroll
    for(int k=0;k<8;k++){ y1[k] = cmul(buf[aS1 + 4352 + 544*k], tw); tw = cmul(tw, wAc); } }
  dft8i<1>(y1);
  {
    float2 twi = conjf2(w1);
    const float2 stepi = make_float2(0.92387953251f, 0.38268343236f);
    float2 ph = make_float2(tL[8*512+t], tL[9*512+t]);
    const float2 phstep = make_float2(0.98078528040f, -0.19509032202f);
    #pragma unroll
    for(int q=0;q<8;q++){
      float2 z0 = y0[SIG[q]];
      float2 z1 = cmul(y1[SIG[q]], twi);
      float2 yn = cscale(cadd(z0,z1), sc2);
      float2 ym = cscale(csub(z0,z1), sc2);
      float qn = fmaf(ph.x, yn.x,  ph.y*yn.y);
      float qm = fmaf(ph.y, ym.x, -ph.x*ym.y);
      if (SIGMA) {
        float bq = bL[q*512+t], bq8 = bL[(q+8)*512+t];
        loc -= bq*qn + bq8*qm;
      } else {
        float bn = bL[q*512+t] - qn;
        bL[q*512+t] = bn; loc = fmaf(bn,bn,loc);
        bn = bL[(q+8)*512+t] - qm;
        bL[(q+8)*512+t] = bn; loc = fmaf(bn,bn,loc);
      }
      twi = cmul(twi, stepi); ph = cmul(ph, phstep);
    }
  }
}

// P2/P4: B -> C -> mid -> C-inv -> B-inv, wave-internal (fences, no barriers).
template<int MODE> // 1 = G junction, 2 = S junction
__device__ __forceinline__ void p2_mid(float2* buf, const float* tL, int t,
                                       int aB, int aC, int aM8,
                                       const float4* j0, const float4* j1){
  #pragma clang loop unroll(disable)
  for(int h=0;h<2;++h){
    float2 wB = make_float2(tL[4*512+t], tL[5*512+t]);
    fwd_stage8<68,false>(buf, aB + 4352*h, wB);
  }
  wfence();
  #pragma clang loop unroll(disable)
  for(int h=0;h<2;++h){
    float2 wC = make_float2(tL[6*512+t], tL[7*512+t]);
    fwd_stage8<8,true>(buf, aC + 4352*h, wC);
  }
  wfence();
  #pragma clang loop unroll(disable)
  for(int h=0;h<2;++h){
    if (MODE==1) mid_junction_g8(buf, aM8 + 4352*h, h ? j1 : j0);
    else         mid_junction_s8(buf, aM8 + 4352*h, h ? j1 : j0);
  }
  wfence();
  #pragma clang loop unroll(disable)
  for(int h=0;h<2;++h){
    float2 wCc = make_float2(tL[6*512+t], -tL[7*512+t]);
    inv_stage8<8,true>(buf, aC + 4352*h, wCc);
  }
  wfence();
  #pragma clang loop unroll(disable)
  for(int h=0;h<2;++h){
    float2 wBc = make_float2(tL[4*512+t], -tL[5*512+t]);
    inv_stage8<68,false>(buf, aB + 4352*h, wBc);
  }
}

// One full iteration: 4 block barriers + 2 reduction barriers (was 16).
template<bool SIGMA>
__device__ __forceinline__ float iterate(float2* buf, float* red, float* bL, const float* tL,
                                         int t, int aS1, int aB, int aC, int aM8,
                                         const float4* gx4, const float4* gc4,
                                         const float4* sb4){
  const float sc1 = 1.f/8192.f, sc2 = 1.f/8192.f;
  float loc = 0.f;

  p1_s1_a_fwd(buf, bL, tL, t, aS1);
  __syncthreads();                                   // A out -> B in (cross-wave)
  p2_mid<1>(buf, tL, t, aB, aC, aM8, gx4 + 4*t, gc4 + 4*t);
  __syncthreads();                                   // B-inv out -> A-inv in
  p3_ainv_junc_afwd<SIGMA>(buf, bL, tL, t, aS1, loc, sc1);
  __syncthreads();
  p2_mid<2>(buf, tL, t, aB, aC, aM8, sb4 + 2*t, sb4 + 1024 + 2*t);
  __syncthreads();
  p5_ainv_final<SIGMA>(buf, bL, tL, t, aS1, loc, sc2);

  __syncthreads();
  #pragma unroll
  for(int off=32; off; off>>=1) loc += __shfl_down(loc, off, 64);
  if((t&63)==0) red[t>>6] = loc;
  __syncthreads();
  float tot = 0.f;
  #pragma unroll
  for(int w=0;w<8;w++) tot += red[w];
  __syncthreads();
  return tot;
}

__global__ void msvl_zero(float* out){ out[0] = 0.f; }

__global__ void __launch_bounds__(512)
msvl_main(float* x, float* circ, float* b0, float* out){
  __shared__ float2 buf[BUFSZ];        // 69,632 B
  __shared__ float red[8];
  __shared__ float bL[16*512];         // 32,768 B  breg columns
  __shared__ float tL[10*512];         // 20,480 B  twiddle stash
  const int t = threadIdx.x;
  const int row = blockIdx.x;

  float* xrow = x    + (size_t)row * NN;
  float* crow = circ + (size_t)row * NN;
  float* brow = b0   + (size_t)row * NN;

  // Padded per-thread bases (iteration-invariant).
  const int aS1 = t + (t>>4);                              // S1 / stage-A base
  const int aB  = (t>>6)*544 + (t&63) + ((t&63)>>4);       // stage B
  const int aC  = (t>>3)*68 + (t&7);                       // stage C
  const int aM8 = 8*t + (t>>1);                            // mid blocks

  // Twiddle scalars: computed once, stashed to LDS.
  float s1v,c1v,sAv,cAv,sBv,cBv,sCv,cCv,psv,pcv;
  __sincosf(-6.28318530718f*(float)t/8192.f,       &s1v,&c1v);   // w1 (S1)
  __sincosf(-6.28318530718f*(float)t/4096.f,       &sAv,&cAv);   // wA (st=512)
  __sincosf(-6.28318530718f*(float)(t&63)/512.f,   &sBv,&cBv);   // wB (st=64)
  __sincosf(-6.28318530718f*(float)(t&7)/64.f,     &sCv,&cCv);   // wC (st=8)
  __sincosf(-3.14159265359f*(float)t/8192.f,       &psv,&pcv);   // phi
  const float2 phstep = make_float2(0.98078528040f, -0.19509032202f);
  tL[0*512+t]=c1v; tL[1*512+t]=s1v;
  tL[2*512+t]=cAv; tL[3*512+t]=sAv;
  tL[4*512+t]=cBv; tL[5*512+t]=sBv;
  tL[6*512+t]=cCv; tL[7*512+t]=sCv;
  tL[8*512+t]=pcv; tL[9*512+t]=psv;

  // --- init: b = b0 / ||b0|| -> bL  (precedes spectra overwrite of brow) ----
  {
    float nrm = 0.f;
    #pragma unroll
    for(int j=0;j<16;j++){ float v = brow[t+512*j]; bL[j*512+t]=v; nrm = fmaf(v,v,nrm); }
    #pragma unroll
    for(int off=32; off; off>>=1) nrm += __shfl_down(nrm, off, 64);
    if((t&63)==0) red[t>>6] = nrm;
    __syncthreads();
    float tot = 0.f;
    #pragma unroll
    for(int w=0;w<8;w++) tot += red[w];
    float isc = rsqrtf(tot);
    #pragma unroll
    for(int j=0;j<16;j++) bL[j*512+t] *= isc;
  }

  // --- precompute spectra (3 forward FFTs) -> global (full barriers, 1x) ----
  // G: gx[8t+j] (xrow), gc[8t+j] (crow);  S2o: brow[8t+j], brow[4096+8t+j].
  {
    const float2 w1 = make_float2(c1v,s1v), wA = make_float2(cAv,sAv),
                 wB = make_float2(cBv,sBv), wC = make_float2(cCv,sCv);
    float fj[16], dj[16];
    #pragma unroll
    for(int j=0;j<16;j++){
      int n = t + 512*j;
      float xn = xrow[n];
      float xr = (n==0) ? 0.f : xrow[NN - n];
      fj[j] = xn + xr;
      dj[j] = xn - xr;
    }
    // FFT(f) -> 0.5*S2e (register se[16])
    fwd_s1_real(buf, aS1, fj, w1);
    __syncthreads();
    #pragma clang loop unroll(disable)
    for(int h=0; h<2; ++h) fwd_stage8<544,false>(buf, aS1 + 4352*h, wA);
    __syncthreads();
    #pragma clang loop unroll(disable)
    for(int h=0; h<2; ++h) fwd_stage8<68,false>(buf, aB + 4352*h, wB);
    __syncthreads();
    #pragma clang loop unroll(disable)
    for(int h=0; h<2; ++h) fwd_stage8<8,true>(buf, aC + 4352*h, wC);
    __syncthreads();
    #pragma clang loop unroll(disable)
    for(int h=0; h<2; ++h) fwd_stage_last8(buf, aM8 + 4352*h);
    __syncthreads();
    float se[16];
    #pragma unroll
    for(int j=0;j<8;j++){ se[j] = 0.5f * buf[aM8 + j].x; se[8+j] = 0.5f * buf[aM8 + 4352 + j].x; }
    __syncthreads();
    // FFT(d*phi) -> 0.5*S2o -> brow
    {
      float2 ph = make_float2(pcv, psv);
      float2 tmp[16];
      #pragma unroll
      for(int j=0;j<16;j++){ tmp[j] = make_float2(dj[j]*ph.x, dj[j]*ph.y); ph = cmul(ph, phstep); }
      fwd_s1_cplx(buf, aS1, tmp, w1);
    }
    __syncthreads();
    #pragma clang loop unroll(disable)
    for(int h=0; h<2; ++h) fwd_stage8<544,false>(buf, aS1 + 4352*h, wA);
    __syncthreads();
    #pragma clang loop unroll(disable)
    for(int h=0; h<2; ++h) fwd_stage8<68,false>(buf, aB + 4352*h, wB);
    __syncthreads();
    #pragma clang loop unroll(disable)
    for(int h=0; h<2; ++h) fwd_stage8<8,true>(buf, aC + 4352*h, wC);
    __syncthreads();
    #pragma clang loop unroll(disable)
    for(int h=0; h<2; ++h) fwd_stage_last8(buf, aM8 + 4352*h);
    __syncthreads();
    #pragma unroll
    for(int j=0;j<8;j++){
      brow[8*t + j]        = 0.5f * buf[aM8 + j].x;
      brow[4096 + 8*t + j] = 0.5f * buf[aM8 + 4352 + j].x;
    }
    __syncthreads();
    // FFT(c) -> Fc; G = Fc*(1 + i*se) -> gx (xrow) / gc (crow)
    #pragma unroll
    for(int j=0;j<16;j++) fj[j] = crow[t+512*j];
    fwd_s1_real(buf, aS1, fj, w1);
    __syncthreads();
    #pragma clang loop unroll(disable)
    for(int h=0; h<2; ++h) fwd_stage8<544,false>(buf, aS1 + 4352*h, wA);
    __syncthreads();
    #pragma clang loop unroll(disable)
    for(int h=0; h<2; ++h) fwd_stage8<68,false>(buf, aB + 4352*h, wB);
    __syncthreads();
    #pragma clang loop unroll(disable)
    for(int h=0; h<2; ++h) fwd_stage8<8,true>(buf, aC + 4352*h, wC);
    __syncthreads();
    #pragma clang loop unroll(disable)
    for(int h=0; h<2; ++h) fwd_stage_last8(buf, aM8 + 4352*h);
    __syncthreads();
    {
      float2* gx = (float2*)xrow;
      float2* gc = (float2*)crow;
      #pragma unroll
      for(int j=0;j<8;j++){
        float2 f0 = buf[aM8 + j];
        float2 f1 = buf[aM8 + 4352 + j];
        gx[8*t + j] = make_float2(fmaf(-f0.y, se[j],   f0.x), fmaf(f0.x, se[j],   f0.y));
        gc[8*t + j] = make_float2(fmaf(-f1.y, se[8+j], f1.x), fmaf(f1.x, se[8+j], f1.y));
      }
    }
    __syncthreads();
  }

  const float4* gx4 = (const float4*)xrow;
  const float4* gc4 = (const float4*)crow;
  const float4* sb4 = (const float4*)brow;

  // --- 100 power iterations (rolled) ----------------------------------------
  #pragma clang loop unroll(disable)
  for(int iter=0; iter<100; ++iter){
    asm volatile("" ::: "memory");   // no cross-iteration hoisting of LDS state
    float tot = iterate<false>(buf, red, bL, tL, t, aS1, aB, aC, aM8,
                               gx4, gc4, sb4);
    float s = rsqrtf(tot);
    #pragma unroll
    for(int j=0;j<16;j++) bL[j*512+t] *= s;
  }

  // --- final matvec for sigma ------------------------------------------------
  {
    asm volatile("" ::: "memory");
    float tot = iterate<true>(buf, red, bL, tL, t, aS1, aB, aC, aM8,
                              gx4, gc4, sb4);
    if(t == 0) atomicAdd(out, fabsf(tot) * (1.f/512.f));
  }
}

extern "C" void kernel_launch(void* const* d_in, const int* in_sizes, int n_in,
                              void* d_out, int out_size, void* d_ws, size_t ws_size,
                              hipStream_t stream) {
  float* x    = (float*)d_in[0];
  float* circ = (float*)d_in[1];
  float* b0   = (float*)d_in[2];
  float* out  = (float*)d_out;

  hipLaunchKernelGGL(msvl_zero, dim3(1), dim3(1), 0, stream, out);
  hipLaunchKernelGGL(msvl_main, dim3(ROWS), dim3(NT), 0, stream,
                     x, circ, b0, out);
}

// Round 10
// 2992.289 us; speedup vs baseline: 5.9515x; 1.0623x over previous
//
#include <hip/hip_runtime.h>
#include <math.h>

// 512 rows of length 8192. Power iteration b <- normalize(b - T(x)C(c)b), 100x,
// then sigma = b.(b - TCb); out = mean(|sigma|).
//
// ROUND 20 KEY CHANGE: twiddle-power tables in LDS, serial chains deleted.
// r19 left the kernel VALU-issue-bound (VALUBusy 72%, HBM ~0, 1 block/CU
// pinned by LDS). Static audit: ~24 serial twiddle chains per iteration
// (tw = cmul(tw,w) x7, ~23 instr + 24-cycle dependent latency each) ~= 550
// VALU instr/thread/iter, unhideable at 2 waves/SIMD.
// Fix: tables tA[7x512] (wA^j per thread), tB[7x64] (per t&63), tC[7x8]
// (per t&7), filled ONCE in the prologue by the bitwise-identical chain;
// stages read w^j (stride-1 / broadcast layouts = conflict floor). Inverse
// stages use conj(table) — bitwise equal to the old conj-chains (conj
// distributes exactly over the cmul chain). P3's twi chain replaced by
// conj(twf) (bitwise). S1/phi chains kept (cheap, bitwise-preserving).
// LDS: 69,632(buf)+32(red)+32,768(bL)+4,096(w1L)+4,096(phL)
//      +28,672(tA)+3,584(tB)+448(tC) = 143,328 B (1 block/CU, as before).
//
// Radix-8 DIF math (verified r16-r19, absmax 0):
//   dft8: a[k]=y[k]+y[k+4]; b[k]=(y[k]-y[k+4])*W8^{Dk},
//         W8^{D}={1,(C2,D*C2),(0,D),(-C2,D*C2)}; dft4(a)->even, dft4(b)->odd.
//   Bin j lands at y[SIG[j]], SIG={0,4,1,5,2,6,3,7}; both directions store
//   slot j <- y[SIG[j]].
//
// LDS padding a(e) = e + (e>>4); padded affine offsets (carry-checked):
//   S1/A:    a = t+(t>>4) + 544k, mirror +4352
//   stage B: a = (t>>6)*544 + (t&63)+((t&63)>>4) + 68k
//   stage C: a = (t>>3)*68 + (t&7) + 8k + (k>>1)
//   mid:     a = 8t + (t>>1) + k
//   half1 of any stage: +4352 (= pad(e+4096)-pad(e)).
//
// Barrier topology (r19): 4 block barriers + 2 reduction barriers per iter;
// B/C/mid exchanges are wave-internal -> compile-time fences only.

#define NN 8192
#define NT 512
#define ROWS 512
#define BUFSZ 8704   // 8192 + 512 pad (float2)

__device__ __forceinline__ float2 cadd(float2 a, float2 b){ return make_float2(a.x+b.x, a.y+b.y); }
__device__ __forceinline__ float2 csub(float2 a, float2 b){ return make_float2(a.x-b.x, a.y-b.y); }
__device__ __forceinline__ float2 cmul(float2 a, float2 b){
  return make_float2(fmaf(a.x, b.x, -(a.y*b.y)), fmaf(a.x, b.y, a.y*b.x));
}
__device__ __forceinline__ float2 cscale(float2 a, float s){ return make_float2(a.x*s, a.y*s); }
__device__ __forceinline__ float2 conjf2(float2 a){ return make_float2(a.x, -a.y); }

// Wave-internal ordering fence (r19): no runtime cost; forbids reordering of
// LDS ops. Same-wave ds ops are processed in order by the LDS pipe.
__device__ __forceinline__ void wfence(){
  asm volatile("" ::: "memory");
  __builtin_amdgcn_sched_barrier(0);
}

static constexpr int SIG[8] = {0,4,1,5,2,6,3,7};   // bin j lives at y[SIG[j]]

template<int DIR> // DIR = -1 forward, +1 inverse
__device__ __forceinline__ void dft4(float2& a, float2& b, float2& c, float2& d){
  float2 t0=cadd(a,c), t1=csub(a,c), t2=cadd(b,d), t3=csub(b,d);
  float2 it3 = make_float2((float)(-DIR)*t3.y, (float)DIR*t3.x);
  a = cadd(t0,t2);
  c = csub(t0,t2);
  b = cadd(t1,it3);
  d = csub(t1,it3);
}

template<int DIR>
__device__ __forceinline__ void dft8i(float2 y[8]){
  const float C2 = 0.70710678119f;
  const float D  = (float)DIR;
  float2 a0=cadd(y[0],y[4]), a1=cadd(y[1],y[5]), a2=cadd(y[2],y[6]), a3=cadd(y[3],y[7]);
  float2 b0=csub(y[0],y[4]), b1=csub(y[1],y[5]), b2=csub(y[2],y[6]), b3=csub(y[3],y[7]);
  b1 = cmul(b1, make_float2(C2, D*C2));
  b2 = make_float2(-D*b2.y, D*b2.x);              // * (0, D)
  b3 = cmul(b3, make_float2(-C2, D*C2));
  dft4<DIR>(a0,a1,a2,a3);                          // even bins (natural)
  dft4<DIR>(b0,b1,b2,b3);                          // odd bins (natural)
  y[0]=a0; y[1]=a1; y[2]=a2; y[3]=a3;
  y[4]=b0; y[5]=b1; y[6]=b2; y[7]=b3;
}

// Padded offset within a stage: STEP*k (+ k>>1 for the st=8 stage).
template<int STEP, bool HK>
__device__ __forceinline__ constexpr int off8(int k){ return STEP*k + (HK ? (k>>1) : 0); }

// Forward radix-8 stage, twiddles from LDS table twp[(j-1)*TS] = w^j.
// j=0 store is a plain copy (old cmul by (1,0) was exact).
template<int STEP, bool HK, int TS>
__device__ __forceinline__ void fwd_stage8_t(float2* buf, int a0, const float2* twp){
  float2 y[8];
  #pragma unroll
  for(int k=0;k<8;k++) y[k] = buf[a0 + off8<STEP,HK>(k)];
  dft8i<-1>(y);
  buf[a0] = y[SIG[0]];
  #pragma unroll
  for(int j=1;j<8;j++) buf[a0 + off8<STEP,HK>(j)] = cmul(y[SIG[j]], twp[(j-1)*TS]);
}

// Inverse radix-8 stage: load bin k * conj(w^k) from table, inverse network.
template<int STEP, bool HK, int TS>
__device__ __forceinline__ void inv_stage8_t(float2* buf, int a0, const float2* twp){
  float2 y[8];
  y[0] = buf[a0];
  #pragma unroll
  for(int k=1;k<8;k++) y[k] = cmul(buf[a0 + off8<STEP,HK>(k)], conjf2(twp[(k-1)*TS]));
  dft8i<1>(y);
  #pragma unroll
  for(int j=0;j<8;j++) buf[a0 + off8<STEP,HK>(j)] = y[SIG[j]];
}

// Last forward stage (precompute only): slot j <- bin j.
__device__ __forceinline__ void fwd_stage_last8(float2* buf, int aM){
  float2 y[8];
  #pragma unroll
  for(int k=0;k<8;k++) y[k] = buf[aM + k];
  dft8i<-1>(y);
  #pragma unroll
  for(int j=0;j<8;j++) buf[aM + j] = y[SIG[j]];
}

// Fused: fwd-last + complex-spectrum multiply (G) + inv-first.
__device__ __forceinline__ void mid_junction_g8(float2* buf, int aM, const float4* gp){
  float2 y[8];
  #pragma unroll
  for(int k=0;k<8;k++) y[k] = buf[aM + k];
  dft8i<-1>(y);
  float2 z[8];
  #pragma unroll
  for(int j2=0;j2<4;j2++){
    float4 g = gp[j2];
    z[2*j2]   = cmul(y[SIG[2*j2]],   make_float2(g.x, g.y));
    z[2*j2+1] = cmul(y[SIG[2*j2+1]], make_float2(g.z, g.w));
  }
  dft8i<1>(z);
  #pragma unroll
  for(int k=0;k<8;k++) buf[aM + k] = z[SIG[k]];
}

// Fused: fwd-last + real-spectrum multiply + inv-first.
__device__ __forceinline__ void mid_junction_s8(float2* buf, int aM, const float4* sp){
  float2 y[8];
  #pragma unroll
  for(int k=0;k<8;k++) y[k] = buf[aM + k];
  dft8i<-1>(y);
  float2 z[8];
  float4 s0 = sp[0], s1 = sp[1];
  z[0] = cscale(y[SIG[0]], s0.x);
  z[1] = cscale(y[SIG[1]], s0.y);
  z[2] = cscale(y[SIG[2]], s0.z);
  z[3] = cscale(y[SIG[3]], s0.w);
  z[4] = cscale(y[SIG[4]], s1.x);
  z[5] = cscale(y[SIG[5]], s1.y);
  z[6] = cscale(y[SIG[6]], s1.z);
  z[7] = cscale(y[SIG[7]], s1.w);
  dft8i<1>(z);
  #pragma unroll
  for(int k=0;k<8;k++) buf[aM + k] = z[SIG[k]];
}

// ---- precompute-only S1 helpers (write LDS; barrier follows) ---------------

__device__ __forceinline__ void fwd_s1_real(float2* buf, int aS1, const float b[16], float2 w1){
  float2 tw = w1;
  const float2 step = make_float2(0.92387953251f, -0.38268343236f); // e^{-i pi/8}
  #pragma unroll
  for(int q=0;q<8;q++){
    int a = aS1 + 544*q;
    float d = b[q] - b[q+8];
    buf[a]        = make_float2(b[q] + b[q+8], 0.f);
    buf[a + 4352] = make_float2(d*tw.x, d*tw.y);
    tw = cmul(tw, step);
  }
}

__device__ __forceinline__ void fwd_s1_cplx(float2* buf, int aS1, const float2 in[16], float2 w1){
  float2 tw = w1;
  const float2 step = make_float2(0.92387953251f, -0.38268343236f);
  #pragma unroll
  for(int q=0;q<8;q++){
    int a = aS1 + 544*q;
    buf[a]        = cadd(in[q], in[q+8]);
    buf[a + 4352] = cmul(csub(in[q], in[q+8]), tw);
    tw = cmul(tw, step);
  }
}

// ---- in-loop fused phases ---------------------------------------------------

// P1: S1-fwd (from bL) + stage-A-fwd (table twiddles), both halves.
__device__ __forceinline__ void p1_s1_a_fwd(float2* buf, const float* bL, const float* w1L,
                                            const float2* tAt, int t, int aS1){
  float2 w1 = make_float2(w1L[t], w1L[512+t]);
  float2 n[8], m[8];
  {
    float2 tw = w1;
    const float2 step = make_float2(0.92387953251f, -0.38268343236f);
    #pragma unroll
    for(int q=0;q<8;q++){
      float bq = bL[q*512+t], bq8 = bL[(q+8)*512+t];
      float d = bq - bq8;
      n[q] = make_float2(bq + bq8, 0.f);
      m[q] = make_float2(d*tw.x, d*tw.y);
      tw = cmul(tw, step);
    }
  }
  dft8i<-1>(n);
  buf[aS1] = n[SIG[0]];
  #pragma unroll
  for(int j=1;j<8;j++) buf[aS1 + 544*j] = cmul(n[SIG[j]], tAt[(j-1)*512]);
  dft8i<-1>(m);
  buf[aS1 + 4352] = m[SIG[0]];
  #pragma unroll
  for(int j=1;j<8;j++) buf[aS1 + 4352 + 544*j] = cmul(m[SIG[j]], tAt[(j-1)*512]);
}

// P3: A-inv + inv-S1 + epilogue1 + phi-modulate + S1-fwd + A-fwd.
template<bool SIGMA>
__device__ __forceinline__ void p3_ainv_junc_afwd(float2* buf, float* bL, const float* w1L,
                                                  const float* phL, const float2* tAt,
                                                  int t, int aS1, float& loc, float sc1){
  float2 w1 = make_float2(w1L[t], w1L[512+t]);
  float2 y0[8], y1[8];
  y0[0] = buf[aS1];
  #pragma unroll
  for(int k=1;k<8;k++) y0[k] = cmul(buf[aS1 + 544*k], conjf2(tAt[(k-1)*512]));
  dft8i<1>(y0);
  y1[0] = buf[aS1 + 4352];
  #pragma unroll
  for(int k=1;k<8;k++) y1[k] = cmul(buf[aS1 + 4352 + 544*k], conjf2(tAt[(k-1)*512]));
  dft8i<1>(y1);
  // time sample at slot q: half0 = y0[SIG[q]], half1 = y1[SIG[q]]
  float2 n[8], m[8];
  {
    float2 twf = w1;
    const float2 stepf = make_float2(0.92387953251f, -0.38268343236f);
    float2 ph = make_float2(phL[t], phL[512+t]);
    const float2 phstep = make_float2(0.98078528040f, -0.19509032202f);
    #pragma unroll
    for(int q=0;q<8;q++){
      float2 twi = conjf2(twf);          // bitwise == old conj-chain
      float2 z0 = y0[SIG[q]];
      float2 z1 = cmul(y1[SIG[q]], twi);
      float2 zn = cscale(cadd(z0,z1), sc1);
      float2 zm = cscale(csub(z0,z1), sc1);
      if (SIGMA) {
        float bq = bL[q*512+t], bq8 = bL[(q+8)*512+t];
        loc += bq*(bq-zn.y) + bq8*(bq8-zm.y);
      } else {
        bL[q*512+t]     -= zn.y;
        bL[(q+8)*512+t] -= zm.y;
      }
      float2 vn = make_float2(zn.x*ph.x,  zn.x*ph.y);
      float2 vm = make_float2(zm.x*ph.y, -zm.x*ph.x);
      n[q] = cadd(vn, vm);
      m[q] = cmul(csub(vn, vm), twf);
      twf = cmul(twf, stepf); ph = cmul(ph, phstep);
    }
  }
  dft8i<-1>(n);
  buf[aS1] = n[SIG[0]];
  #pragma unroll
  for(int j=1;j<8;j++) buf[aS1 + 544*j] = cmul(n[SIG[j]], tAt[(j-1)*512]);
  dft8i<-1>(m);
  buf[aS1 + 4352] = m[SIG[0]];
  #pragma unroll
  for(int j=1;j<8;j++) buf[aS1 + 4352 + 544*j] = cmul(m[SIG[j]], tAt[(j-1)*512]);
}

// P5: A-inv + inv-S1 + epilogue2 (updates bL, loc).
template<bool SIGMA>
__device__ __forceinline__ void p5_ainv_final(float2* buf, float* bL, const float* w1L,
                                              const float* phL, const float2* tAt,
                                              int t, int aS1, float& loc, float sc2){
  float2 w1 = make_float2(w1L[t], w1L[512+t]);
  float2 y0[8], y1[8];
  y0[0] = buf[aS1];
  #pragma unroll
  for(int k=1;k<8;k++) y0[k] = cmul(buf[aS1 + 544*k], conjf2(tAt[(k-1)*512]));
  dft8i<1>(y0);
  y1[0] = buf[aS1 + 4352];
  #pragma unroll
  for(int k=1;k<8;k++) y1[k] = cmul(buf[aS1 + 4352 + 544*k], conjf2(tAt[(k-1)*512]));
  dft8i<1>(y1);
  {
    float2 twf = w1;
    const float2 stepf = make_float2(0.92387953251f, -0.38268343236f);
    float2 ph = make_float2(phL[t], phL[512+t]);
    const float2 phstep = make_float2(0.98078528040f, -0.19509032202f);
    #pragma unroll
    for(int q=0;q<8;q++){
      float2 twi = conjf2(twf);
      float2 z0 = y0[SIG[q]];
      float2 z1 = cmul(y1[SIG[q]], twi);
      float2 yn = cscale(cadd(z0,z1), sc2);
      float2 ym = cscale(csub(z0,z1), sc2);
      float qn = fmaf(ph.x, yn.x,  ph.y*yn.y);
      float qm = fmaf(ph.y, ym.x, -ph.x*ym.y);
      if (SIGMA) {
        float bq = bL[q*512+t], bq8 = bL[(q+8)*512+t];
        loc -= bq*qn + bq8*qm;
      } else {
        float bn = bL[q*512+t] - qn;
        bL[q*512+t] = bn; loc = fmaf(bn,bn,loc);
        bn = bL[(q+8)*512+t] - qm;
        bL[(q+8)*512+t] = bn; loc = fmaf(bn,bn,loc);
      }
      twf = cmul(twf, stepf); ph = cmul(ph, phstep);
    }
  }
}

// P2/P4: B -> C -> mid -> C-inv -> B-inv, wave-internal (fences, no barriers).
template<int MODE> // 1 = G junction, 2 = S junction
__device__ __forceinline__ void p2_mid(float2* buf, const float2* tBt, const float2* tCt,
                                       int aB, int aC, int aM8,
                                       const float4* j0, const float4* j1){
  #pragma clang loop unroll(disable)
  for(int h=0;h<2;++h) fwd_stage8_t<68,false,64>(buf, aB + 4352*h, tBt);
  wfence();
  #pragma clang loop unroll(disable)
  for(int h=0;h<2;++h) fwd_stage8_t<8,true,8>(buf, aC + 4352*h, tCt);
  wfence();
  #pragma clang loop unroll(disable)
  for(int h=0;h<2;++h){
    if (MODE==1) mid_junction_g8(buf, aM8 + 4352*h, h ? j1 : j0);
    else         mid_junction_s8(buf, aM8 + 4352*h, h ? j1 : j0);
  }
  wfence();
  #pragma clang loop unroll(disable)
  for(int h=0;h<2;++h) inv_stage8_t<8,true,8>(buf, aC + 4352*h, tCt);
  wfence();
  #pragma clang loop unroll(disable)
  for(int h=0;h<2;++h) inv_stage8_t<68,false,64>(buf, aB + 4352*h, tBt);
}

// One full iteration: 4 block barriers + 2 reduction barriers.
template<bool SIGMA>
__device__ __forceinline__ float iterate(float2* buf, float* red, float* bL,
                                         const float* w1L, const float* phL,
                                         const float2* tAt, const float2* tBt, const float2* tCt,
                                         int t, int aS1, int aB, int aC, int aM8,
                                         const float4* gx4, const float4* gc4,
                                         const float4* sb4){
  const float sc1 = 1.f/8192.f, sc2 = 1.f/8192.f;
  float loc = 0.f;

  p1_s1_a_fwd(buf, bL, w1L, tAt, t, aS1);
  __syncthreads();                                   // A out -> B in (cross-wave)
  p2_mid<1>(buf, tBt, tCt, aB, aC, aM8, gx4 + 4*t, gc4 + 4*t);
  __syncthreads();                                   // B-inv out -> A-inv in
  p3_ainv_junc_afwd<SIGMA>(buf, bL, w1L, phL, tAt, t, aS1, loc, sc1);
  __syncthreads();
  p2_mid<2>(buf, tBt, tCt, aB, aC, aM8, sb4 + 2*t, sb4 + 1024 + 2*t);
  __syncthreads();
  p5_ainv_final<SIGMA>(buf, bL, w1L, phL, tAt, t, aS1, loc, sc2);

  __syncthreads();
  #pragma unroll
  for(int off=32; off; off>>=1) loc += __shfl_down(loc, off, 64);
  if((t&63)==0) red[t>>6] = loc;
  __syncthreads();
  float tot = 0.f;
  #pragma unroll
  for(int w=0;w<8;w++) tot += red[w];
  __syncthreads();
  return tot;
}

__global__ void msvl_zero(float* out){ out[0] = 0.f; }

__global__ void __launch_bounds__(512)
msvl_main(float* x, float* circ, float* b0, float* out){
  __shared__ float2 buf[BUFSZ];        // 69,632 B
  __shared__ float red[8];
  __shared__ float bL[16*512];         // 32,768 B  breg columns
  __shared__ float w1L[2*512];         //  4,096 B  (c1,s1)
  __shared__ float phL[2*512];         //  4,096 B  (pc,ps)
  __shared__ float2 tA[7*512];         // 28,672 B  wA^j per thread
  __shared__ float2 tB[7*64];          //  3,584 B  wB^j per (t&63)
  __shared__ float2 tC[7*8];           //    448 B  wC^j per (t&7)
  const int t = threadIdx.x;
  const int row = blockIdx.x;

  float* xrow = x    + (size_t)row * NN;
  float* crow = circ + (size_t)row * NN;
  float* brow = b0   + (size_t)row * NN;

  // Padded per-thread bases (iteration-invariant).
  const int aS1 = t + (t>>4);                              // S1 / stage-A base
  const int aB  = (t>>6)*544 + (t&63) + ((t&63)>>4);       // stage B
  const int aC  = (t>>3)*68 + (t&7);                       // stage C
  const int aM8 = 8*t + (t>>1);                            // mid blocks

  // Twiddle scalars: computed once; power tables filled by the SAME cmul
  // chain the stages used before (bitwise-identical values).
  float s1v,c1v,sAv,cAv,sBv,cBv,sCv,cCv,psv,pcv;
  __sincosf(-6.28318530718f*(float)t/8192.f,       &s1v,&c1v);   // w1 (S1)
  __sincosf(-6.28318530718f*(float)t/4096.f,       &sAv,&cAv);   // wA (st=512)
  __sincosf(-6.28318530718f*(float)(t&63)/512.f,   &sBv,&cBv);   // wB (st=64)
  __sincosf(-6.28318530718f*(float)(t&7)/64.f,     &sCv,&cCv);   // wC (st=8)
  __sincosf(-3.14159265359f*(float)t/8192.f,       &psv,&pcv);   // phi
  const float2 phstep = make_float2(0.98078528040f, -0.19509032202f);
  w1L[t]=c1v; w1L[512+t]=s1v;
  phL[t]=pcv; phL[512+t]=psv;
  {
    float2 w = make_float2(cAv,sAv), tw = w;
    #pragma unroll
    for(int j=1;j<8;j++){ tA[(j-1)*512 + t] = tw; tw = cmul(tw, w); }
  }
  if (t < 64) {
    float2 w = make_float2(cBv,sBv), tw = w;
    #pragma unroll
    for(int j=1;j<8;j++){ tB[(j-1)*64 + t] = tw; tw = cmul(tw, w); }
  }
  if (t < 8) {
    float2 w = make_float2(cCv,sCv), tw = w;
    #pragma unroll
    for(int j=1;j<8;j++){ tC[(j-1)*8 + t] = tw; tw = cmul(tw, w); }
  }

  const float2* tAt = tA + t;
  const float2* tBt = tB + (t&63);
  const float2* tCt = tC + (t&7);

  // --- init: b = b0 / ||b0|| -> bL  (barriers here also publish the tables) -
  {
    float nrm = 0.f;
    #pragma unroll
    for(int j=0;j<16;j++){ float v = brow[t+512*j]; bL[j*512+t]=v; nrm = fmaf(v,v,nrm); }
    #pragma unroll
    for(int off=32; off; off>>=1) nrm += __shfl_down(nrm, off, 64);
    if((t&63)==0) red[t>>6] = nrm;
    __syncthreads();
    float tot = 0.f;
    #pragma unroll
    for(int w=0;w<8;w++) tot += red[w];
    float isc = rsqrtf(tot);
    #pragma unroll
    for(int j=0;j<16;j++) bL[j*512+t] *= isc;
  }

  // --- precompute spectra (3 forward FFTs) -> global ------------------------
  // G: gx[8t+j] (xrow), gc[8t+j] (crow);  S2o: brow[8t+j], brow[4096+8t+j].
  {
    const float2 w1 = make_float2(c1v,s1v);
    float fj[16], dj[16];
    #pragma unroll
    for(int j=0;j<16;j++){
      int n = t + 512*j;
      float xn = xrow[n];
      float xr = (n==0) ? 0.f : xrow[NN - n];
      fj[j] = xn + xr;
      dj[j] = xn - xr;
    }
    // FFT(f) -> 0.5*S2e (register se[16])
    fwd_s1_real(buf, aS1, fj, w1);
    __syncthreads();
    #pragma clang loop unroll(disable)
    for(int h=0; h<2; ++h) fwd_stage8_t<544,false,512>(buf, aS1 + 4352*h, tAt);
    __syncthreads();
    #pragma clang loop unroll(disable)
    for(int h=0; h<2; ++h) fwd_stage8_t<68,false,64>(buf, aB + 4352*h, tBt);
    __syncthreads();
    #pragma clang loop unroll(disable)
    for(int h=0; h<2; ++h) fwd_stage8_t<8,true,8>(buf, aC + 4352*h, tCt);
    __syncthreads();
    #pragma clang loop unroll(disable)
    for(int h=0; h<2; ++h) fwd_stage_last8(buf, aM8 + 4352*h);
    __syncthreads();
    float se[16];
    #pragma unroll
    for(int j=0;j<8;j++){ se[j] = 0.5f * buf[aM8 + j].x; se[8+j] = 0.5f * buf[aM8 + 4352 + j].x; }
    __syncthreads();
    // FFT(d*phi) -> 0.5*S2o -> brow
    {
      float2 ph = make_float2(pcv, psv);
      float2 tmp[16];
      #pragma unroll
      for(int j=0;j<16;j++){ tmp[j] = make_float2(dj[j]*ph.x, dj[j]*ph.y); ph = cmul(ph, phstep); }
      fwd_s1_cplx(buf, aS1, tmp, w1);
    }
    __syncthreads();
    #pragma clang loop unroll(disable)
    for(int h=0; h<2; ++h) fwd_stage8_t<544,false,512>(buf, aS1 + 4352*h, tAt);
    __syncthreads();
    #pragma clang loop unroll(disable)
    for(int h=0; h<2; ++h) fwd_stage8_t<68,false,64>(buf, aB + 4352*h, tBt);
    __syncthreads();
    #pragma clang loop unroll(disable)
    for(int h=0; h<2; ++h) fwd_stage8_t<8,true,8>(buf, aC + 4352*h, tCt);
    __syncthreads();
    #pragma clang loop unroll(disable)
    for(int h=0; h<2; ++h) fwd_stage_last8(buf, aM8 + 4352*h);
    __syncthreads();
    #pragma unroll
    for(int j=0;j<8;j++){
      brow[8*t + j]        = 0.5f * buf[aM8 + j].x;
      brow[4096 + 8*t + j] = 0.5f * buf[aM8 + 4352 + j].x;
    }
    __syncthreads();
    // FFT(c) -> Fc; G = Fc*(1 + i*se) -> gx (xrow) / gc (crow)
    #pragma unroll
    for(int j=0;j<16;j++) fj[j] = crow[t+512*j];
    fwd_s1_real(buf, aS1, fj, w1);
    __syncthreads();
    #pragma clang loop unroll(disable)
    for(int h=0; h<2; ++h) fwd_stage8_t<544,false,512>(buf, aS1 + 4352*h, tAt);
    __syncthreads();
    #pragma clang loop unroll(disable)
    for(int h=0; h<2; ++h) fwd_stage8_t<68,false,64>(buf, aB + 4352*h, tBt);
    __syncthreads();
    #pragma clang loop unroll(disable)
    for(int h=0; h<2; ++h) fwd_stage8_t<8,true,8>(buf, aC + 4352*h, tCt);
    __syncthreads();
    #pragma clang loop unroll(disable)
    for(int h=0; h<2; ++h) fwd_stage_last8(buf, aM8 + 4352*h);
    __syncthreads();
    {
      float2* gx = (float2*)xrow;
      float2* gc = (float2*)crow;
      #pragma unroll
      for(int j=0;j<8;j++){
        float2 f0 = buf[aM8 + j];
        float2 f1 = buf[aM8 + 4352 + j];
        gx[8*t + j] = make_float2(fmaf(-f0.y, se[j],   f0.x), fmaf(f0.x, se[j],   f0.y));
        gc[8*t + j] = make_float2(fmaf(-f1.y, se[8+j], f1.x), fmaf(f1.x, se[8+j], f1.y));
      }
    }
    __syncthreads();
  }

  const float4* gx4 = (const float4*)xrow;
  const float4* gc4 = (const float4*)crow;
  const float4* sb4 = (const float4*)brow;

  // --- 100 power iterations (rolled) ----------------------------------------
  #pragma clang loop unroll(disable)
  for(int iter=0; iter<100; ++iter){
    asm volatile("" ::: "memory");   // no cross-iteration hoisting of LDS state
    float tot = iterate<false>(buf, red, bL, w1L, phL, tAt, tBt, tCt,
                               t, aS1, aB, aC, aM8, gx4, gc4, sb4);
    float s = rsqrtf(tot);
    #pragma unroll
    for(int j=0;j<16;j++) bL[j*512+t] *= s;
  }

  // --- final matvec for sigma ------------------------------------------------
  {
    asm volatile("" ::: "memory");
    float tot = iterate<true>(buf, red, bL, w1L, phL, tAt, tBt, tCt,
                              t, aS1, aB, aC, aM8, gx4, gc4, sb4);
    if(t == 0) atomicAdd(out, fabsf(tot) * (1.f/512.f));
  }
}

extern "C" void kernel_launch(void* const* d_in, const int* in_sizes, int n_in,
                              void* d_out, int out_size, void* d_ws, size_t ws_size,
                              hipStream_t stream) {
  float* x    = (float*)d_in[0];
  float* circ = (float*)d_in[1];
  float* b0   = (float*)d_in[2];
  float* out  = (float*)d_out;

  hipLaunchKernelGGL(msvl_zero, dim3(1), dim3(1), 0, stream, out);
  hipLaunchKernelGGL(msvl_main, dim3(ROWS), dim3(NT), 0, stream,
                     x, circ, b0, out);
}

// Round 11
// 2850.504 us; speedup vs baseline: 6.2476x; 1.0497x over previous
//
#include <hip/hip_runtime.h>
#include <math.h>

// 512 rows of length 8192. Power iteration b <- normalize(b - T(x)C(c)b), 100x,
// then sigma = b.(b - TCb); out = mean(|sigma|).
//
// ROUND 21 KEY CHANGE: 2 blocks/CU via small-LDS footprint. r20 left the
// kernel latency-bound: VALUBusy 62% (down from 72% while time only -6% ->
// VALU no longer binding), HBM ~0, occupancy pinned at 24% (1 block/CU,
// 2 waves/SIMD) -- too few waves to hide LDS latency. Residency math after
// the spill fix (r18: scratch eliminated, WRITE 49 MB): buf = 69,632 B, so
// TWO blocks fit in 160 KB LDS iff per-block extras <= ~12 KB. r20's extras
// (bL 32K + tA 28K + w1L/phL 8K) forced 1 block. Fix:
//   - breg[16] back to VGPRs (phase peak ~90 at VGPR=100 -> +16 fits <128,
//     the 4-waves/SIMD cap the allocator has always targeted at 512t).
//   - w1/wA/phi = 6 persistent regs, asm-pinned per iteration (blocks LICM
//     from hoisting derived chains/loads -- the r18 spill lesson).
//   - tA dropped -> stage-A twiddles via r19's serial chains (8 chains/iter
//     re-added ~340 VALU instr; the B/C tables -- 16 of 24 chains -- stay).
//   - LDS per block: 69,632(buf) + 32(red) + 3,584(tB) + 448(tC) = 73,696 B.
// Expect occupancy 24 -> ~47%. CANARY: WRITE_SIZE must stay ~49 MB; a jump
// to GBs means pressure blew the cap (revert breg to LDS).
//
// Radix-8 DIF math (verified r16-r20, absmax 0):
//   dft8: a[k]=y[k]+y[k+4]; b[k]=(y[k]-y[k+4])*W8^{Dk},
//         W8^{D}={1,(C2,D*C2),(0,D),(-C2,D*C2)}; dft4(a)->even, dft4(b)->odd.
//   Bin j lands at y[SIG[j]], SIG={0,4,1,5,2,6,3,7}; both directions store
//   slot j <- y[SIG[j]].
//
// LDS padding a(e) = e + (e>>4); padded affine offsets (carry-checked):
//   S1/A:    a = t+(t>>4) + 544k, mirror +4352
//   stage B: a = (t>>6)*544 + (t&63)+((t&63)>>4) + 68k
//   stage C: a = (t>>3)*68 + (t&7) + 8k + (k>>1)
//   mid:     a = 8t + (t>>1) + k
//   half1 of any stage: +4352 (= pad(e+4096)-pad(e)).
//
// Barrier topology (r19): 4 block barriers + 2 reduction barriers per iter;
// B/C/mid exchanges are wave-internal -> compile-time fences only.

#define NN 8192
#define NT 512
#define ROWS 512
#define BUFSZ 8704   // 8192 + 512 pad (float2)

__device__ __forceinline__ float2 cadd(float2 a, float2 b){ return make_float2(a.x+b.x, a.y+b.y); }
__device__ __forceinline__ float2 csub(float2 a, float2 b){ return make_float2(a.x-b.x, a.y-b.y); }
__device__ __forceinline__ float2 cmul(float2 a, float2 b){
  return make_float2(fmaf(a.x, b.x, -(a.y*b.y)), fmaf(a.x, b.y, a.y*b.x));
}
__device__ __forceinline__ float2 cscale(float2 a, float s){ return make_float2(a.x*s, a.y*s); }
__device__ __forceinline__ float2 conjf2(float2 a){ return make_float2(a.x, -a.y); }

// Wave-internal ordering fence (r19): no runtime cost; forbids reordering of
// LDS ops. Same-wave ds ops are processed in order by the LDS pipe.
__device__ __forceinline__ void wfence(){
  asm volatile("" ::: "memory");
  __builtin_amdgcn_sched_barrier(0);
}

static constexpr int SIG[8] = {0,4,1,5,2,6,3,7};   // bin j lives at y[SIG[j]]

template<int DIR> // DIR = -1 forward, +1 inverse
__device__ __forceinline__ void dft4(float2& a, float2& b, float2& c, float2& d){
  float2 t0=cadd(a,c), t1=csub(a,c), t2=cadd(b,d), t3=csub(b,d);
  float2 it3 = make_float2((float)(-DIR)*t3.y, (float)DIR*t3.x);
  a = cadd(t0,t2);
  c = csub(t0,t2);
  b = cadd(t1,it3);
  d = csub(t1,it3);
}

template<int DIR>
__device__ __forceinline__ void dft8i(float2 y[8]){
  const float C2 = 0.70710678119f;
  const float D  = (float)DIR;
  float2 a0=cadd(y[0],y[4]), a1=cadd(y[1],y[5]), a2=cadd(y[2],y[6]), a3=cadd(y[3],y[7]);
  float2 b0=csub(y[0],y[4]), b1=csub(y[1],y[5]), b2=csub(y[2],y[6]), b3=csub(y[3],y[7]);
  b1 = cmul(b1, make_float2(C2, D*C2));
  b2 = make_float2(-D*b2.y, D*b2.x);              // * (0, D)
  b3 = cmul(b3, make_float2(-C2, D*C2));
  dft4<DIR>(a0,a1,a2,a3);                          // even bins (natural)
  dft4<DIR>(b0,b1,b2,b3);                          // odd bins (natural)
  y[0]=a0; y[1]=a1; y[2]=a2; y[3]=a3;
  y[4]=b0; y[5]=b1; y[6]=b2; y[7]=b3;
}

// Padded offset within a stage: STEP*k (+ k>>1 for the st=8 stage).
template<int STEP, bool HK>
__device__ __forceinline__ constexpr int off8(int k){ return STEP*k + (HK ? (k>>1) : 0); }

// Forward radix-8 stage, chain twiddles (stage A + precompute).
template<int STEP, bool HK>
__device__ __forceinline__ void fwd_stage8(float2* buf, int a0, float2 w){
  float2 y[8];
  #pragma unroll
  for(int k=0;k<8;k++) y[k] = buf[a0 + off8<STEP,HK>(k)];
  dft8i<-1>(y);
  float2 tw = make_float2(1.f,0.f);
  #pragma unroll
  for(int j=0;j<8;j++){
    buf[a0 + off8<STEP,HK>(j)] = cmul(y[SIG[j]], tw);
    tw = cmul(tw, w);
  }
}

// Forward radix-8 stage, twiddles from LDS table twp[(j-1)*TS] = w^j (B/C).
template<int STEP, bool HK, int TS>
__device__ __forceinline__ void fwd_stage8_t(float2* buf, int a0, const float2* twp){
  float2 y[8];
  #pragma unroll
  for(int k=0;k<8;k++) y[k] = buf[a0 + off8<STEP,HK>(k)];
  dft8i<-1>(y);
  buf[a0] = y[SIG[0]];
  #pragma unroll
  for(int j=1;j<8;j++) buf[a0 + off8<STEP,HK>(j)] = cmul(y[SIG[j]], twp[(j-1)*TS]);
}

// Inverse radix-8 stage, conj(table) twiddles (B/C).
template<int STEP, bool HK, int TS>
__device__ __forceinline__ void inv_stage8_t(float2* buf, int a0, const float2* twp){
  float2 y[8];
  y[0] = buf[a0];
  #pragma unroll
  for(int k=1;k<8;k++) y[k] = cmul(buf[a0 + off8<STEP,HK>(k)], conjf2(twp[(k-1)*TS]));
  dft8i<1>(y);
  #pragma unroll
  for(int j=0;j<8;j++) buf[a0 + off8<STEP,HK>(j)] = y[SIG[j]];
}

// Last forward stage (precompute only): slot j <- bin j.
__device__ __forceinline__ void fwd_stage_last8(float2* buf, int aM){
  float2 y[8];
  #pragma unroll
  for(int k=0;k<8;k++) y[k] = buf[aM + k];
  dft8i<-1>(y);
  #pragma unroll
  for(int j=0;j<8;j++) buf[aM + j] = y[SIG[j]];
}

// Fused: fwd-last + complex-spectrum multiply (G) + inv-first.
__device__ __forceinline__ void mid_junction_g8(float2* buf, int aM, const float4* gp){
  float2 y[8];
  #pragma unroll
  for(int k=0;k<8;k++) y[k] = buf[aM + k];
  dft8i<-1>(y);
  float2 z[8];
  #pragma unroll
  for(int j2=0;j2<4;j2++){
    float4 g = gp[j2];
    z[2*j2]   = cmul(y[SIG[2*j2]],   make_float2(g.x, g.y));
    z[2*j2+1] = cmul(y[SIG[2*j2+1]], make_float2(g.z, g.w));
  }
  dft8i<1>(z);
  #pragma unroll
  for(int k=0;k<8;k++) buf[aM + k] = z[SIG[k]];
}

// Fused: fwd-last + real-spectrum multiply + inv-first.
__device__ __forceinline__ void mid_junction_s8(float2* buf, int aM, const float4* sp){
  float2 y[8];
  #pragma unroll
  for(int k=0;k<8;k++) y[k] = buf[aM + k];
  dft8i<-1>(y);
  float2 z[8];
  float4 s0 = sp[0], s1 = sp[1];
  z[0] = cscale(y[SIG[0]], s0.x);
  z[1] = cscale(y[SIG[1]], s0.y);
  z[2] = cscale(y[SIG[2]], s0.z);
  z[3] = cscale(y[SIG[3]], s0.w);
  z[4] = cscale(y[SIG[4]], s1.x);
  z[5] = cscale(y[SIG[5]], s1.y);
  z[6] = cscale(y[SIG[6]], s1.z);
  z[7] = cscale(y[SIG[7]], s1.w);
  dft8i<1>(z);
  #pragma unroll
  for(int k=0;k<8;k++) buf[aM + k] = z[SIG[k]];
}

// ---- precompute-only S1 helpers (write LDS; barrier follows) ---------------

__device__ __forceinline__ void fwd_s1_real(float2* buf, int aS1, const float b[16], float2 w1){
  float2 tw = w1;
  const float2 step = make_float2(0.92387953251f, -0.38268343236f); // e^{-i pi/8}
  #pragma unroll
  for(int q=0;q<8;q++){
    int a = aS1 + 544*q;
    float d = b[q] - b[q+8];
    buf[a]        = make_float2(b[q] + b[q+8], 0.f);
    buf[a + 4352] = make_float2(d*tw.x, d*tw.y);
    tw = cmul(tw, step);
  }
}

__device__ __forceinline__ void fwd_s1_cplx(float2* buf, int aS1, const float2 in[16], float2 w1){
  float2 tw = w1;
  const float2 step = make_float2(0.92387953251f, -0.38268343236f);
  #pragma unroll
  for(int q=0;q<8;q++){
    int a = aS1 + 544*q;
    buf[a]        = cadd(in[q], in[q+8]);
    buf[a + 4352] = cmul(csub(in[q], in[q+8]), tw);
    tw = cmul(tw, step);
  }
}

// ---- in-loop fused phases (breg in VGPRs; w1/wA/ph in pinned regs) ---------

// P1: S1-fwd (from breg) + stage-A-fwd (chain twiddles), both halves.
__device__ __forceinline__ void p1_s1_a_fwd(float2* buf, const float breg[16],
                                            float2 w1, float2 wA, int aS1){
  float2 n[8], m[8];
  {
    float2 tw = w1;
    const float2 step = make_float2(0.92387953251f, -0.38268343236f);
    #pragma unroll
    for(int q=0;q<8;q++){
      float bq = breg[q], bq8 = breg[q+8];
      float d = bq - bq8;
      n[q] = make_float2(bq + bq8, 0.f);
      m[q] = make_float2(d*tw.x, d*tw.y);
      tw = cmul(tw, step);
    }
  }
  dft8i<-1>(n);
  { float2 tw = make_float2(1.f,0.f);
    #pragma unroll
    for(int j=0;j<8;j++){ buf[aS1 + 544*j] = cmul(n[SIG[j]], tw); tw = cmul(tw, wA); } }
  dft8i<-1>(m);
  { float2 tw = make_float2(1.f,0.f);
    #pragma unroll
    for(int j=0;j<8;j++){ buf[aS1 + 4352 + 544*j] = cmul(m[SIG[j]], tw); tw = cmul(tw, wA); } }
}

// P3: A-inv + inv-S1 + epilogue1 + phi-modulate + S1-fwd + A-fwd.
template<bool SIGMA>
__device__ __forceinline__ void p3_ainv_junc_afwd(float2* buf, float breg[16],
                                                  float2 w1, float2 wA, float2 ph0,
                                                  int aS1, float& loc, float sc1){
  float2 wAc = conjf2(wA);
  float2 y0[8], y1[8];
  { float2 tw = make_float2(1.f,0.f);
    #pragma unroll
    for(int k=0;k<8;k++){ y0[k] = cmul(buf[aS1 + 544*k], tw); tw = cmul(tw, wAc); } }
  dft8i<1>(y0);
  { float2 tw = make_float2(1.f,0.f);
    #pragma unroll
    for(int k=0;k<8;k++){ y1[k] = cmul(buf[aS1 + 4352 + 544*k], tw); tw = cmul(tw, wAc); } }
  dft8i<1>(y1);
  // time sample at slot q: half0 = y0[SIG[q]], half1 = y1[SIG[q]]
  float2 n[8], m[8];
  {
    float2 twf = w1;
    const float2 stepf = make_float2(0.92387953251f, -0.38268343236f);
    float2 ph = ph0;
    const float2 phstep = make_float2(0.98078528040f, -0.19509032202f);
    #pragma unroll
    for(int q=0;q<8;q++){
      float2 twi = conjf2(twf);          // bitwise == old conj-chain
      float2 z0 = y0[SIG[q]];
      float2 z1 = cmul(y1[SIG[q]], twi);
      float2 zn = cscale(cadd(z0,z1), sc1);
      float2 zm = cscale(csub(z0,z1), sc1);
      if (SIGMA) {
        loc += breg[q]*(breg[q]-zn.y) + breg[q+8]*(breg[q+8]-zm.y);
      } else {
        breg[q]   -= zn.y;
        breg[q+8] -= zm.y;
      }
      float2 vn = make_float2(zn.x*ph.x,  zn.x*ph.y);
      float2 vm = make_float2(zm.x*ph.y, -zm.x*ph.x);
      n[q] = cadd(vn, vm);
      m[q] = cmul(csub(vn, vm), twf);
      twf = cmul(twf, stepf); ph = cmul(ph, phstep);
    }
  }
  dft8i<-1>(n);
  { float2 tw = make_float2(1.f,0.f);
    #pragma unroll
    for(int j=0;j<8;j++){ buf[aS1 + 544*j] = cmul(n[SIG[j]], tw); tw = cmul(tw, wA); } }
  dft8i<-1>(m);
  { float2 tw = make_float2(1.f,0.f);
    #pragma unroll
    for(int j=0;j<8;j++){ buf[aS1 + 4352 + 544*j] = cmul(m[SIG[j]], tw); tw = cmul(tw, wA); } }
}

// P5: A-inv + inv-S1 + epilogue2 (updates breg, loc).
template<bool SIGMA>
__device__ __forceinline__ void p5_ainv_final(float2* buf, float breg[16],
                                              float2 w1, float2 wA, float2 ph0,
                                              int aS1, float& loc, float sc2){
  float2 wAc = conjf2(wA);
  float2 y0[8], y1[8];
  { float2 tw = make_float2(1.f,0.f);
    #pragma unroll
    for(int k=0;k<8;k++){ y0[k] = cmul(buf[aS1 + 544*k], tw); tw = cmul(tw, wAc); } }
  dft8i<1>(y0);
  { float2 tw = make_float2(1.f,0.f);
    #pragma unroll
    for(int k=0;k<8;k++){ y1[k] = cmul(buf[aS1 + 4352 + 544*k], tw); tw = cmul(tw, wAc); } }
  dft8i<1>(y1);
  {
    float2 twf = w1;
    const float2 stepf = make_float2(0.92387953251f, -0.38268343236f);
    float2 ph = ph0;
    const float2 phstep = make_float2(0.98078528040f, -0.19509032202f);
    #pragma unroll
    for(int q=0;q<8;q++){
      float2 twi = conjf2(twf);
      float2 z0 = y0[SIG[q]];
      float2 z1 = cmul(y1[SIG[q]], twi);
      float2 yn = cscale(cadd(z0,z1), sc2);
      float2 ym = cscale(csub(z0,z1), sc2);
      float qn = fmaf(ph.x, yn.x,  ph.y*yn.y);
      float qm = fmaf(ph.y, ym.x, -ph.x*ym.y);
      if (SIGMA) {
        loc -= breg[q]*qn + breg[q+8]*qm;
      } else {
        float bn = breg[q] - qn;
        breg[q] = bn; loc = fmaf(bn,bn,loc);
        bn = breg[q+8] - qm;
        breg[q+8] = bn; loc = fmaf(bn,bn,loc);
      }
      twf = cmul(twf, stepf); ph = cmul(ph, phstep);
    }
  }
}

// P2/P4: B -> C -> mid -> C-inv -> B-inv, wave-internal (fences, no barriers).
template<int MODE> // 1 = G junction, 2 = S junction
__device__ __forceinline__ void p2_mid(float2* buf, const float2* tBt, const float2* tCt,
                                       int aB, int aC, int aM8,
                                       const float4* j0, const float4* j1){
  #pragma clang loop unroll(disable)
  for(int h=0;h<2;++h) fwd_stage8_t<68,false,64>(buf, aB + 4352*h, tBt);
  wfence();
  #pragma clang loop unroll(disable)
  for(int h=0;h<2;++h) fwd_stage8_t<8,true,8>(buf, aC + 4352*h, tCt);
  wfence();
  #pragma clang loop unroll(disable)
  for(int h=0;h<2;++h){
    if (MODE==1) mid_junction_g8(buf, aM8 + 4352*h, h ? j1 : j0);
    else         mid_junction_s8(buf, aM8 + 4352*h, h ? j1 : j0);
  }
  wfence();
  #pragma clang loop unroll(disable)
  for(int h=0;h<2;++h) inv_stage8_t<8,true,8>(buf, aC + 4352*h, tCt);
  wfence();
  #pragma clang loop unroll(disable)
  for(int h=0;h<2;++h) inv_stage8_t<68,false,64>(buf, aB + 4352*h, tBt);
}

// One full iteration: 4 block barriers + 2 reduction barriers.
template<bool SIGMA>
__device__ __forceinline__ float iterate(float2* buf, float* red, float breg[16],
                                         const float2* tBt, const float2* tCt,
                                         int t, int aS1, int aB, int aC, int aM8,
                                         float2 w1, float2 wA, float2 ph0,
                                         const float4* gx4, const float4* gc4,
                                         const float4* sb4){
  const float sc1 = 1.f/8192.f, sc2 = 1.f/8192.f;
  float loc = 0.f;

  p1_s1_a_fwd(buf, breg, w1, wA, aS1);
  __syncthreads();                                   // A out -> B in (cross-wave)
  p2_mid<1>(buf, tBt, tCt, aB, aC, aM8, gx4 + 4*t, gc4 + 4*t);
  __syncthreads();                                   // B-inv out -> A-inv in
  p3_ainv_junc_afwd<SIGMA>(buf, breg, w1, wA, ph0, aS1, loc, sc1);
  __syncthreads();
  p2_mid<2>(buf, tBt, tCt, aB, aC, aM8, sb4 + 2*t, sb4 + 1024 + 2*t);
  __syncthreads();
  p5_ainv_final<SIGMA>(buf, breg, w1, wA, ph0, aS1, loc, sc2);

  __syncthreads();
  #pragma unroll
  for(int off=32; off; off>>=1) loc += __shfl_down(loc, off, 64);
  if((t&63)==0) red[t>>6] = loc;
  __syncthreads();
  float tot = 0.f;
  #pragma unroll
  for(int w=0;w<8;w++) tot += red[w];
  __syncthreads();
  return tot;
}

__global__ void msvl_zero(float* out){ out[0] = 0.f; }

__global__ void __launch_bounds__(512)
msvl_main(float* x, float* circ, float* b0, float* out){
  __shared__ float2 buf[BUFSZ];        // 69,632 B
  __shared__ float red[8];
  __shared__ float2 tB[7*64];          //  3,584 B  wB^j per (t&63)
  __shared__ float2 tC[7*8];           //    448 B  wC^j per (t&7)
  // total 73,696 B -> 2 blocks/CU
  const int t = threadIdx.x;
  const int row = blockIdx.x;

  float* xrow = x    + (size_t)row * NN;
  float* crow = circ + (size_t)row * NN;
  float* brow = b0   + (size_t)row * NN;

  // Padded per-thread bases (iteration-invariant).
  const int aS1 = t + (t>>4);                              // S1 / stage-A base
  const int aB  = (t>>6)*544 + (t&63) + ((t&63)>>4);       // stage B
  const int aC  = (t>>3)*68 + (t&7);                       // stage C
  const int aM8 = 8*t + (t>>1);                            // mid blocks

  // Twiddle scalars; B/C power tables filled once (bitwise-identical chains).
  float s1v,c1v,sAv,cAv,sBv,cBv,sCv,cCv,psv,pcv;
  __sincosf(-6.28318530718f*(float)t/8192.f,       &s1v,&c1v);   // w1 (S1)
  __sincosf(-6.28318530718f*(float)t/4096.f,       &sAv,&cAv);   // wA (st=512)
  __sincosf(-6.28318530718f*(float)(t&63)/512.f,   &sBv,&cBv);   // wB (st=64)
  __sincosf(-6.28318530718f*(float)(t&7)/64.f,     &sCv,&cCv);   // wC (st=8)
  __sincosf(-3.14159265359f*(float)t/8192.f,       &psv,&pcv);   // phi
  const float2 phstep = make_float2(0.98078528040f, -0.19509032202f);
  if (t < 64) {
    float2 w = make_float2(cBv,sBv), tw = w;
    #pragma unroll
    for(int j=1;j<8;j++){ tB[(j-1)*64 + t] = tw; tw = cmul(tw, w); }
  }
  if (t < 8) {
    float2 w = make_float2(cCv,sCv), tw = w;
    #pragma unroll
    for(int j=1;j<8;j++){ tC[(j-1)*8 + t] = tw; tw = cmul(tw, w); }
  }

  const float2* tBt = tB + (t&63);
  const float2* tCt = tC + (t&7);

  float breg[16];

  // --- init: b = b0 / ||b0||  (barriers here also publish the tables) ------
  {
    float nrm = 0.f;
    #pragma unroll
    for(int j=0;j<16;j++){ float v = brow[t+512*j]; breg[j]=v; nrm = fmaf(v,v,nrm); }
    #pragma unroll
    for(int off=32; off; off>>=1) nrm += __shfl_down(nrm, off, 64);
    if((t&63)==0) red[t>>6] = nrm;
    __syncthreads();
    float tot = 0.f;
    #pragma unroll
    for(int w=0;w<8;w++) tot += red[w];
    float isc = rsqrtf(tot);
    #pragma unroll
    for(int j=0;j<16;j++) breg[j] *= isc;
  }

  // --- precompute spectra (3 forward FFTs) -> global ------------------------
  // G: gx[8t+j] (xrow), gc[8t+j] (crow);  S2o: brow[8t+j], brow[4096+8t+j].
  {
    const float2 w1 = make_float2(c1v,s1v), wA = make_float2(cAv,sAv);
    float fj[16], dj[16];
    #pragma unroll
    for(int j=0;j<16;j++){
      int n = t + 512*j;
      float xn = xrow[n];
      float xr = (n==0) ? 0.f : xrow[NN - n];
      fj[j] = xn + xr;
      dj[j] = xn - xr;
    }
    // FFT(f) -> 0.5*S2e (register se[16])
    fwd_s1_real(buf, aS1, fj, w1);
    __syncthreads();
    #pragma clang loop unroll(disable)
    for(int h=0; h<2; ++h) fwd_stage8<544,false>(buf, aS1 + 4352*h, wA);
    __syncthreads();
    #pragma clang loop unroll(disable)
    for(int h=0; h<2; ++h) fwd_stage8_t<68,false,64>(buf, aB + 4352*h, tBt);
    __syncthreads();
    #pragma clang loop unroll(disable)
    for(int h=0; h<2; ++h) fwd_stage8_t<8,true,8>(buf, aC + 4352*h, tCt);
    __syncthreads();
    #pragma clang loop unroll(disable)
    for(int h=0; h<2; ++h) fwd_stage_last8(buf, aM8 + 4352*h);
    __syncthreads();
    float se[16];
    #pragma unroll
    for(int j=0;j<8;j++){ se[j] = 0.5f * buf[aM8 + j].x; se[8+j] = 0.5f * buf[aM8 + 4352 + j].x; }
    __syncthreads();
    // FFT(d*phi) -> 0.5*S2o -> brow
    {
      float2 ph = make_float2(pcv, psv);
      float2 tmp[16];
      #pragma unroll
      for(int j=0;j<16;j++){ tmp[j] = make_float2(dj[j]*ph.x, dj[j]*ph.y); ph = cmul(ph, phstep); }
      fwd_s1_cplx(buf, aS1, tmp, w1);
    }
    __syncthreads();
    #pragma clang loop unroll(disable)
    for(int h=0; h<2; ++h) fwd_stage8<544,false>(buf, aS1 + 4352*h, wA);
    __syncthreads();
    #pragma clang loop unroll(disable)
    for(int h=0; h<2; ++h) fwd_stage8_t<68,false,64>(buf, aB + 4352*h, tBt);
    __syncthreads();
    #pragma clang loop unroll(disable)
    for(int h=0; h<2; ++h) fwd_stage8_t<8,true,8>(buf, aC + 4352*h, tCt);
    __syncthreads();
    #pragma clang loop unroll(disable)
    for(int h=0; h<2; ++h) fwd_stage_last8(buf, aM8 + 4352*h);
    __syncthreads();
    #pragma unroll
    for(int j=0;j<8;j++){
      brow[8*t + j]        = 0.5f * buf[aM8 + j].x;
      brow[4096 + 8*t + j] = 0.5f * buf[aM8 + 4352 + j].x;
    }
    __syncthreads();
    // FFT(c) -> Fc; G = Fc*(1 + i*se) -> gx (xrow) / gc (crow)
    #pragma unroll
    for(int j=0;j<16;j++) fj[j] = crow[t+512*j];
    fwd_s1_real(buf, aS1, fj, w1);
    __syncthreads();
    #pragma clang loop unroll(disable)
    for(int h=0; h<2; ++h) fwd_stage8<544,false>(buf, aS1 + 4352*h, wA);
    __syncthreads();
    #pragma clang loop unroll(disable)
    for(int h=0; h<2; ++h) fwd_stage8_t<68,false,64>(buf, aB + 4352*h, tBt);
    __syncthreads();
    #pragma clang loop unroll(disable)
    for(int h=0; h<2; ++h) fwd_stage8_t<8,true,8>(buf, aC + 4352*h, tCt);
    __syncthreads();
    #pragma clang loop unroll(disable)
    for(int h=0; h<2; ++h) fwd_stage_last8(buf, aM8 + 4352*h);
    __syncthreads();
    {
      float2* gx = (float2*)xrow;
      float2* gc = (float2*)crow;
      #pragma unroll
      for(int j=0;j<8;j++){
        float2 f0 = buf[aM8 + j];
        float2 f1 = buf[aM8 + 4352 + j];
        gx[8*t + j] = make_float2(fmaf(-f0.y, se[j],   f0.x), fmaf(f0.x, se[j],   f0.y));
        gc[8*t + j] = make_float2(fmaf(-f1.y, se[8+j], f1.x), fmaf(f1.x, se[8+j], f1.y));
      }
    }
    __syncthreads();
  }

  const float4* gx4 = (const float4*)xrow;
  const float4* gc4 = (const float4*)crow;
  const float4* sb4 = (const float4*)brow;

  // --- 100 power iterations (rolled) ----------------------------------------
  #pragma clang loop unroll(disable)
  for(int iter=0; iter<100; ++iter){
    // Pin the 6 persistent twiddle scalars (blocks LICM of derived chains)
    // + memory clobber (blocks hoisting of the loop-invariant G/S loads).
    asm volatile("" : "+v"(c1v), "+v"(s1v), "+v"(cAv), "+v"(sAv),
                      "+v"(pcv), "+v"(psv));
    asm volatile("" ::: "memory");
    const float2 w1 = make_float2(c1v,s1v), wA = make_float2(cAv,sAv),
                 ph0 = make_float2(pcv,psv);
    float tot = iterate<false>(buf, red, breg, tBt, tCt,
                               t, aS1, aB, aC, aM8, w1, wA, ph0, gx4, gc4, sb4);
    float s = rsqrtf(tot);
    #pragma unroll
    for(int j=0;j<16;j++) breg[j] *= s;
  }

  // --- final matvec for sigma ------------------------------------------------
  {
    asm volatile("" : "+v"(c1v), "+v"(s1v), "+v"(cAv), "+v"(sAv),
                      "+v"(pcv), "+v"(psv));
    asm volatile("" ::: "memory");
    const float2 w1 = make_float2(c1v,s1v), wA = make_float2(cAv,sAv),
                 ph0 = make_float2(pcv,psv);
    float tot = iterate<true>(buf, red, breg, tBt, tCt,
                              t, aS1, aB, aC, aM8, w1, wA, ph0, gx4, gc4, sb4);
    if(t == 0) atomicAdd(out, fabsf(tot) * (1.f/512.f));
  }
}

extern "C" void kernel_launch(void* const* d_in, const int* in_sizes, int n_in,
                              void* d_out, int out_size, void* d_ws, size_t ws_size,
                              hipStream_t stream) {
  float* x    = (float*)d_in[0];
  float* circ = (float*)d_in[1];
  float* b0   = (float*)d_in[2];
  float* out  = (float*)d_out;

  hipLaunchKernelGGL(msvl_zero, dim3(1), dim3(1), 0, stream, out);
  hipLaunchKernelGGL(msvl_main, dim3(ROWS), dim3(NT), 0, stream,
                     x, circ, b0, out);
}